// Round 8
// baseline (711.459 us; speedup 1.0000x reference)
//
#include <hip/hip_runtime.h>
#include <hip/hip_bf16.h>

typedef unsigned short u16;
typedef short bf16x8 __attribute__((ext_vector_type(8)));
typedef float f32x4 __attribute__((ext_vector_type(4)));

__device__ __forceinline__ float b2f(u16 u) {
  union { float f; unsigned int i; } v; v.i = ((unsigned int)u) << 16; return v.f;
}
__device__ __forceinline__ u16 f2b(float f) {
  union { float f; unsigned int i; } v; v.f = f;
  unsigned int r = v.i + 0x7fffu + ((v.i >> 16) & 1u);
  return (u16)(r >> 16);
}
__device__ __forceinline__ u16 to_b(float v) { return f2b(v); }
__device__ __forceinline__ u16 to_b(u16 v) { return v; }
__device__ __forceinline__ float to_f(float v) { return v; }
__device__ __forceinline__ float to_f(u16 v) { return b2f(v); }

// async 16B global -> LDS (dest = uniform lds base + lane*16)
__device__ __forceinline__ void gl_lds16(const u16* g, u16* l) {
  __builtin_amdgcn_global_load_lds(
      (const __attribute__((address_space(1))) unsigned int*)g,
      (__attribute__((address_space(3))) unsigned int*)l, 16, 0, 0);
}

// ---------------- generic NT GEMM (verified) ----------------
template <bool RELU, bool ATOMIC>
__global__ __launch_bounds__(256)
void gemm_nt(const u16* __restrict__ A, const u16* __restrict__ Bt,
             const float* __restrict__ bias, void* __restrict__ Cv,
             int N, int K, int nsplit, int lda, int ldb, int ldc,
             long sA, long sB, long sC, float scale) {
  __shared__ __align__(16) u16 As[128 * 64];
  __shared__ __align__(16) u16 Bs[128 * 64];
  const int z = blockIdx.z;
  const int batch = z / nsplit, split = z - batch * nsplit;
  const int Ks = K / nsplit;
  const u16* Ab = A + (long)batch * sA + (long)split * Ks;
  const u16* Bb = Bt + (long)batch * sB + (long)split * Ks;
  const int m0 = blockIdx.y * 128, n0 = blockIdx.x * 128;
  const int t = threadIdx.x, w = t >> 6, lane = t & 63;
  const int wm = (w >> 1) * 64, wn = (w & 1) * 64;
  const int lr = lane & 15, q = lane >> 4;

  int srow[4], scol[4];
#pragma unroll
  for (int i = 0; i < 4; i++) {
    int n = w * 256 + i * 64 + lane;
    srow[i] = n >> 3;
    scol[i] = (((n & 7) ^ ((n >> 3) & 7)) * 8);
  }

  f32x4 acc[4][4];
#pragma unroll
  for (int i = 0; i < 4; i++)
#pragma unroll
    for (int j = 0; j < 4; j++) acc[i][j] = (f32x4){0.f, 0.f, 0.f, 0.f};

  for (int k0 = 0; k0 < Ks; k0 += 64) {
#pragma unroll
    for (int i = 0; i < 4; i++)
      gl_lds16(Ab + (long)(m0 + srow[i]) * lda + k0 + scol[i], &As[(w * 256 + i * 64) * 8]);
#pragma unroll
    for (int i = 0; i < 4; i++)
      gl_lds16(Bb + (long)(n0 + srow[i]) * ldb + k0 + scol[i], &Bs[(w * 256 + i * 64) * 8]);
    __syncthreads();
#pragma unroll
    for (int kk = 0; kk < 2; kk++) {
      bf16x8 af[4], bfr[4];
#pragma unroll
      for (int i = 0; i < 4; i++) {
        int row = wm + i * 16 + lr;
        af[i] = *(const bf16x8*)&As[row * 64 + (((kk * 4 + q) ^ (row & 7)) * 8)];
      }
#pragma unroll
      for (int j = 0; j < 4; j++) {
        int row = wn + j * 16 + lr;
        bfr[j] = *(const bf16x8*)&Bs[row * 64 + (((kk * 4 + q) ^ (row & 7)) * 8)];
      }
#pragma unroll
      for (int i = 0; i < 4; i++)
#pragma unroll
        for (int j = 0; j < 4; j++)
          acc[i][j] = __builtin_amdgcn_mfma_f32_16x16x32_bf16(af[i], bfr[j], acc[i][j], 0, 0, 0);
    }
    __syncthreads();
  }

#pragma unroll
  for (int j = 0; j < 4; j++) {
    int cg = n0 + wn + j * 16 + lr;
    float bb = (!ATOMIC && bias) ? bias[cg] : 0.0f;
#pragma unroll
    for (int i = 0; i < 4; i++) {
      int rbase = m0 + wm + i * 16 + q * 4;
#pragma unroll
      for (int r = 0; r < 4; r++) {
        float vv = acc[i][j][r] * scale;
        if (ATOMIC) {
          atomicAdd((float*)Cv + (long)batch * sC + (long)(rbase + r) * ldc + cg, vv);
        } else {
          vv += bb;
          if (RELU) vv = fmaxf(vv, 0.0f);
          ((u16*)Cv)[(long)batch * sC + (long)(rbase + r) * ldc + cg] = f2b(vv);
        }
      }
    }
  }
}

// ---------------- fused flash attention v12: 2 blocks/CU for cross-block overlap ----------------
// v6/v11 (1 block x 8 waves/CU, 98KB LDS) is LDS-issue-bound with ~29% phase
// overhead (phase 4390 cyc vs 3072 LDS + 1053 MFMA): when all 8 barrier-locked
// waves wait, the CU idles. v12 returns to the v4b 64-row/4-wave block (verified
// structure) so TWO independent blocks co-reside per CU (m114: while block A
// sits at s_barrier, block B computes). Per-CU LDS-read volume is unchanged
// (8 waves x same per-wave stream); the overhead gets hidden.
// Kept from the v6/v11 arc: counted-vmcnt (VMW8 = one 8-op stage in flight),
// Qf-before-STAGE ordering (no in-order drain), setprio, XCD-pinned grid
// (flat%8 = batch*2+half -> per-XCD K/V L2-resident, so 2x staging hits L2).
// LDS = 2x32KB ping-pong + 16KB XOR-swizzled Pb (mask 15; rows wave-private,
// same mapping family as verified v7) = exactly 80KB -> 2 blocks/CU.
// Registers identical to v4b: 128 VGPR + 128 AGPR = the 2-wave/SIMD cap.
#define STAGE_K(kvv, kcc, sel)                                               \
  {                                                                          \
    _Pragma("unroll") for (int rr = 0; rr < 8; rr++)                         \
        gl_lds16(Kbase + (long)((kvv) * 128 + srow[rr]) * 1536 +             \
                     (kcc) * 128 + scol8[rr],                                \
                 &B2[(sel)][ldsd[rr]]);                                      \
  }
#define STAGE_V(kvv, dcc, sel)                                               \
  {                                                                          \
    _Pragma("unroll") for (int rr = 0; rr < 8; rr++)                         \
        gl_lds16(Vtb + (long)((dcc) * 128 + srow[rr]) * 4096 +               \
                     (kvv) * 128 + scol8[rr],                                \
                 &B2[(sel)][ldsd[rr]]);                                      \
  }
#define VMW8()  asm volatile("s_waitcnt vmcnt(8)" ::: "memory")
#define VMW0()  asm volatile("s_waitcnt vmcnt(0)" ::: "memory")
#define CFENCE() asm volatile("" ::: "memory")

__global__ __launch_bounds__(256, 2)
void flash_attn(const u16* __restrict__ QKV, const u16* __restrict__ Vt,
                u16* __restrict__ attp, float* __restrict__ lbp, float scl) {
  __shared__ __align__(16) u16 B2[2][128 * 128];  // 2 x 32 KB ping-pong (K/V chunks)
  __shared__ __align__(16) u16 Pb[64 * 128];      // 16 KB P, XOR-swizzled (mask 15)
  const int flat = blockIdx.x;                    // 512 blocks
  const int batch = (flat & 7) >> 1, half = flat & 1, qt = flat >> 3;  // qt 0..63
  const int t = threadIdx.x, w = t >> 6, lane = t & 63;
  const int lr = lane & 15, q = lane >> 4;
  const long rowbase = (long)batch * 4096 + qt * 64;
  const u16* Qrow  = QKV + (rowbase + w * 16 + lr) * 1536;                  // Q cols [0,512)
  const u16* Kbase = QKV + ((long)batch * 4096 + half * 2048) * 1536 + 512; // K cols [512,1024)
  const u16* Vtb   = Vt + (long)batch * 512 * 4096 + half * 2048;           // [512,4096] ld 4096

  int srow[8], scol8[8], ldsd[8];
#pragma unroll
  for (int rr = 0; rr < 8; rr++) {
    int n = rr * 256 + t;
    srow[rr] = n >> 4;
    scol8[rr] = ((n & 15) ^ ((n >> 4) & 15)) * 8;
    ldsd[rr] = (rr * 256 + w * 64) * 8;  // wave-uniform base; DMA adds lane*16B
  }

  f32x4 O[32];  // O[dc*8+j]: row=q*4+r, col=dc*128 + j*16 + lr
#pragma unroll
  for (int i = 0; i < 32; i++) O[i] = (f32x4){0.f, 0.f, 0.f, 0.f};
  float lsum[4] = {0.f, 0.f, 0.f, 0.f};

  STAGE_K(0, 0, 0);  // prologue: first chunk (8 DMA ops) in flight
  int par = 0;

  for (int kv = 0; kv < 16; kv++) {
    f32x4 S[8];
#pragma unroll
    for (int j = 0; j < 8; j++) S[j] = (f32x4){0.f, 0.f, 0.f, 0.f};

    // ---- QK^T: 4 chunks [128 kv x 128 k]; Qf issued BEFORE next stage ----
#pragma unroll
    for (int kc = 0; kc < 4; kc++) {
      bf16x8 Qf[4];  // older than stage(next) -> VMW8 completes them, no drain
#pragma unroll
      for (int ss = 0; ss < 4; ss++)
        Qf[ss] = *(const bf16x8*)(Qrow + kc * 128 + ss * 32 + q * 8);
      __builtin_amdgcn_sched_barrier(0);
      if (kc < 3) { STAGE_K(kv, kc + 1, par ^ 1); }
      else        { STAGE_V(kv, 0, par ^ 1); }
      VMW8();                          // stage(cur)+Qf done; stage(next) in flight
      __builtin_amdgcn_s_barrier();    // ... block-globally
      CFENCE();
      __builtin_amdgcn_s_setprio(1);
#pragma unroll
      for (int ss = 0; ss < 4; ss++)
#pragma unroll
        for (int j = 0; j < 8; j++) {
          int row = j * 16 + lr;
          bf16x8 Kf = *(const bf16x8*)&B2[par][row * 128 + (((ss * 4 + q) ^ lr) * 8)];
          S[j] = __builtin_amdgcn_mfma_f32_16x16x32_bf16(Qf[ss], Kf, S[j], 0, 0, 0);
        }
      __builtin_amdgcn_s_setprio(0);
      CFENCE();
      __builtin_amdgcn_s_barrier();    // reads done before next DMA overwrites
      par ^= 1;
    }

    // ---- P interlude: swizzled Pb, rows wave-private (no barrier) ----
    float psum[4] = {0.f, 0.f, 0.f, 0.f};
#pragma unroll
    for (int j = 0; j < 8; j++)
#pragma unroll
      for (int r = 0; r < 4; r++) {
        float e = __expf(S[j][r] * scl);
        psum[r] += e;
        int prow = w * 16 + q * 4 + r;      // 0..63, wave-private row group
        int pcol = j * 16 + lr;
        Pb[prow * 128 + (((pcol >> 3) ^ (prow & 15)) * 8) + (pcol & 7)] = f2b(e);
      }
#pragma unroll
    for (int r = 0; r < 4; r++) {
#pragma unroll
      for (int o = 1; o < 16; o <<= 1) psum[r] += __shfl_xor(psum[r], o);
      lsum[r] += psum[r];
    }
    bf16x8 Pf[4];  // A-frag: row=w*16+lr, k=t4*32+q*8 (same-wave write->read)
#pragma unroll
    for (int t4 = 0; t4 < 4; t4++) {
      int prow = w * 16 + lr;              // prow&15 == lr
      Pf[t4] = *(const bf16x8*)&Pb[prow * 128 + (((t4 * 4 + q) ^ lr) * 8)];
    }

    // ---- PV: 4 chunks [128 d x 128 kv]; P-frags reused across chunks ----
#pragma unroll
    for (int dc = 0; dc < 4; dc++) {
      if (dc < 3) {
        STAGE_V(kv, dc + 1, par ^ 1);
        VMW8();
      } else if (kv < 15) {
        STAGE_K(kv + 1, 0, par ^ 1);
        VMW8();
      } else {
        VMW0();                        // final phase: nothing new in flight
      }
      __builtin_amdgcn_s_barrier();
      CFENCE();
      __builtin_amdgcn_s_setprio(1);
#pragma unroll
      for (int t4 = 0; t4 < 4; t4++)
#pragma unroll
        for (int j = 0; j < 8; j++) {
          int row = j * 16 + lr;
          bf16x8 Vf = *(const bf16x8*)&B2[par][row * 128 + (((t4 * 4 + q) ^ lr) * 8)];
          O[dc * 8 + j] = __builtin_amdgcn_mfma_f32_16x16x32_bf16(Pf[t4], Vf, O[dc * 8 + j], 0, 0, 0);
        }
      __builtin_amdgcn_s_setprio(0);
      CFENCE();
      __builtin_amdgcn_s_barrier();
      par ^= 1;
    }
  }

  // ---- epilogue: bf16 partial-O stores (no atomics) ----
  u16* op = attp + (long)half * 16384 * 512;
#pragma unroll
  for (int i = 0; i < 32; i++) {
    int col = (i >> 3) * 128 + (i & 7) * 16 + lr;
#pragma unroll
    for (int r = 0; r < 4; r++)
      op[(rowbase + w * 16 + q * 4 + r) * 512 + col] = f2b(O[i][r]);
  }
  if (lr == 0)
#pragma unroll
    for (int r = 0; r < 4; r++)
      lbp[(long)half * 16384 + rowbase + w * 16 + q * 4 + r] = lsum[r];
}

// ---------------- support kernels ----------------
template <typename TS>
__global__ __launch_bounds__(1024)
void transpose_b(const TS* __restrict__ src, u16* __restrict__ dst,
                 int R, int Cc, int src_ld, long sbs, long dbs) {
  __shared__ u16 tile[32][33];
  int r = blockIdx.y * 32 + threadIdx.y;
  int c = blockIdx.x * 32 + threadIdx.x;
  tile[threadIdx.y][threadIdx.x] = to_b(src[(long)blockIdx.z * sbs + (long)r * src_ld + c]);
  __syncthreads();
  int rr = blockIdx.x * 32 + threadIdx.y;
  int cc = blockIdx.y * 32 + threadIdx.x;
  dst[(long)blockIdx.z * dbs + (long)rr * R + cc] = tile[threadIdx.x][threadIdx.y];
}

__global__ __launch_bounds__(256)
void f32_to_bf16(const float* __restrict__ s, u16* __restrict__ d) {
  long i = ((long)blockIdx.x * 256 + threadIdx.x) * 8;
  float4 a0 = *(const float4*)(s + i);
  float4 a1 = *(const float4*)(s + i + 4);
  u16 tmp[8] = {f2b(a0.x), f2b(a0.y), f2b(a0.z), f2b(a0.w),
                f2b(a1.x), f2b(a1.y), f2b(a1.z), f2b(a1.w)};
  *(uint4*)(d + i) = *(uint4*)tmp;
}

// x1 = LN(x + (p0+p1)/l; g,b) -> bf16. Row 512, 1 row/wave.
__global__ __launch_bounds__(256)
void add_ln_att(const float* __restrict__ X, const u16* __restrict__ attp,
                const float* __restrict__ lbp,
                const float* __restrict__ g, const float* __restrict__ b,
                u16* __restrict__ O) {
  const int row = blockIdx.x * 4 + (threadIdx.x >> 6);
  const int lane = threadIdx.x & 63;
  const size_t base = (size_t)row * 512 + lane * 8;
  const float inv = 1.0f / (lbp[row] + lbp[16384 + row]);
  uint4 p0 = *(const uint4*)(attp + base);
  uint4 p1 = *(const uint4*)(attp + 16384L * 512 + base);
  const u16* s0 = (const u16*)&p0;
  const u16* s1 = (const u16*)&p1;
  float z[8];
  float s1a = 0.f, s2a = 0.f;
#pragma unroll
  for (int i = 0; i < 8; i++) {
    z[i] = X[base + i] + (b2f(s0[i]) + b2f(s1[i])) * inv;
    s1a += z[i]; s2a += z[i] * z[i];
  }
#pragma unroll
  for (int o = 32; o > 0; o >>= 1) { s1a += __shfl_xor(s1a, o); s2a += __shfl_xor(s2a, o); }
  const float mu = s1a * (1.0f / 512.0f);
  const float var = s2a * (1.0f / 512.0f) - mu * mu;
  const float rstd = rsqrtf(var + 1e-5f);
#pragma unroll
  for (int i = 0; i < 8; i++) {
    int c = lane * 8 + i;
    O[base + i] = f2b((z[i] - mu) * rstd * g[c] + b[c]);
  }
}

// out = LN(x1 + p0 + p1 + eb; g,b) -> fp32. Row 512, 1 row/wave.
__global__ __launch_bounds__(256)
void add_ln_ffn(const u16* __restrict__ X, const u16* __restrict__ P0,
                const u16* __restrict__ P1, const float* __restrict__ eb,
                const float* __restrict__ g, const float* __restrict__ b,
                float* __restrict__ O) {
  const int row = blockIdx.x * 4 + (threadIdx.x >> 6);
  const int lane = threadIdx.x & 63;
  const size_t base = (size_t)row * 512 + lane * 8;
  uint4 xv = *(const uint4*)(X + base);
  uint4 a0 = *(const uint4*)(P0 + base);
  uint4 a1 = *(const uint4*)(P1 + base);
  const u16* xs = (const u16*)&xv;
  const u16* s0 = (const u16*)&a0;
  const u16* s1 = (const u16*)&a1;
  float z[8];
  float s1a = 0.f, s2a = 0.f;
#pragma unroll
  for (int i = 0; i < 8; i++) {
    int c = lane * 8 + i;
    z[i] = b2f(xs[i]) + b2f(s0[i]) + b2f(s1[i]) + eb[c];
    s1a += z[i]; s2a += z[i] * z[i];
  }
#pragma unroll
  for (int o = 32; o > 0; o >>= 1) { s1a += __shfl_xor(s1a, o); s2a += __shfl_xor(s2a, o); }
  const float mu = s1a * (1.0f / 512.0f);
  const float var = s2a * (1.0f / 512.0f) - mu * mu;
  const float rstd = rsqrtf(var + 1e-5f);
#pragma unroll
  for (int i = 0; i < 8; i++) {
    int c = lane * 8 + i;
    O[base + i] = (z[i] - mu) * rstd * g[c] + b[c];
  }
}

__global__ __launch_bounds__(256)
void concat3(const float* __restrict__ a, const float* __restrict__ b,
             const float* __restrict__ c, float* __restrict__ o) {
  int i = threadIdx.x + blockIdx.x * 256;
  if (i < 512) o[i] = a[i];
  else if (i < 1024) o[i] = b[i - 512];
  else if (i < 1536) o[i] = c[i - 1024];
}

extern "C" void kernel_launch(void* const* d_in, const int* in_sizes, int n_in,
                              void* d_out, int out_size, void* d_ws, size_t ws_size,
                              hipStream_t stream) {
  const float* x   = (const float*)d_in[0];
  const float* Wq  = (const float*)d_in[1];
  const float* bq  = (const float*)d_in[2];
  const float* Wk  = (const float*)d_in[3];
  const float* bk  = (const float*)d_in[4];
  const float* Wv  = (const float*)d_in[5];
  const float* bv  = (const float*)d_in[6];
  const float* g1  = (const float*)d_in[7];
  const float* b1  = (const float*)d_in[8];
  const float* g2  = (const float*)d_in[9];
  const float* b2  = (const float*)d_in[10];
  const float* W1  = (const float*)d_in[11];
  const float* bf1 = (const float*)d_in[12];
  const float* W2  = (const float*)d_in[13];
  const float* bf2 = (const float*)d_in[14];
  float* out = (float*)d_out;

  char* ws = (char*)d_ws;
  const size_t MB = 1048576;
  u16*   QKV   = (u16*)(ws + 0);          // [16384,1536] bf16, 48 MB
  u16*   Vt    = (u16*)(ws + 48 * MB);    // [4,512,4096] bf16, 16 MB
  u16*   attp  = (u16*)(ws + 64 * MB);    // [2][16384,512] bf16 partials, 32 MB
  u16*   h     = (u16*)(ws + 64 * MB);    // [16384,2048] bf16 (after attp dead)
  float* lbp   = (float*)(ws + 128 * MB); // [2][16384] fp32 partial row sums
  u16*   x1    = (u16*)(ws + 129 * MB);   // [16384,512] bf16, 16 MB
  u16*   ffnp  = (u16*)(ws + 145 * MB);   // [2][16384,512] bf16 partials, 32 MB
  u16*   xb    = (u16*)(ws + 145 * MB);   // bf16(x), 16 MB — dead before ffnp written
  u16*   wqkvt = (u16*)(ws + 177 * MB);   // [1536,512] bf16
  u16*   w1t   = wqkvt + 1536 * 512;      // [2048,512] bf16
  u16*   w2t   = w1t + 2048 * 512;        // [512,2048] bf16
  float* bqkv  = (float*)(w2t + 512 * 2048); // [1536] fp32

  dim3 tb(32, 32);
  f32_to_bf16<<<4096, 256, 0, stream>>>(x, xb);
  transpose_b<float><<<dim3(16, 16, 1), tb, 0, stream>>>(Wq, wqkvt,              512, 512, 512, 0, 0);
  transpose_b<float><<<dim3(16, 16, 1), tb, 0, stream>>>(Wk, wqkvt + 512 * 512,  512, 512, 512, 0, 0);
  transpose_b<float><<<dim3(16, 16, 1), tb, 0, stream>>>(Wv, wqkvt + 1024 * 512, 512, 512, 512, 0, 0);
  transpose_b<float><<<dim3(64, 16, 1), tb, 0, stream>>>(W1, w1t, 512, 2048, 2048, 0, 0);
  transpose_b<float><<<dim3(16, 64, 1), tb, 0, stream>>>(W2, w2t, 2048, 512, 512, 0, 0);
  concat3<<<6, 256, 0, stream>>>(bq, bk, bv, bqkv);

  // Fused QKV projection
  gemm_nt<false, false><<<dim3(12, 128, 1), 256, 0, stream>>>(
      xb, wqkvt, bqkv, QKV, 1536, 512, 1, 512, 512, 1536, 0, 0, 0, 1.0f);

  // V^T per batch
  transpose_b<u16><<<dim3(16, 128, 4), tb, 0, stream>>>(
      QKV + 1024, Vt, 4096, 512, 1536, 4096L * 1536, 512L * 4096);

  const float scl = 0.044194173824159216f;  // 1/sqrt(512)
  // Fused attention: 64-row blocks, 2 blocks/CU, counted-vmcnt, XCD-pinned
  flash_attn<<<dim3(512, 1, 1), 256, 0, stream>>>(QKV, Vt, attp, lbp, scl);

  // x1 = LN(x + (p0+p1)/l)
  add_ln_att<<<4096, 256, 0, stream>>>(x, attp, lbp, g1, b1, x1);
  // h = relu(x1 W1 + bf1)   (h overwrites dead attp region)
  gemm_nt<true, false><<<dim3(16, 128, 1), 256, 0, stream>>>(
      x1, w1t, bf1, h, 2048, 512, 1, 512, 512, 2048, 0, 0, 0, 1.0f);
  // ffnp[z] = h[:, z*1024:(z+1)*1024] W2[z*1024:(z+1)*1024, :] (bf16 partials)
  gemm_nt<false, false><<<dim3(4, 128, 2), 256, 0, stream>>>(
      h, w2t, nullptr, ffnp, 512, 1024, 1, 2048, 2048, 512,
      1024, 1024, 16384L * 512, 1.0f);
  // out = LN(x1 + p0 + p1 + bf2) -> fp32
  add_ln_ffn<<<4096, 256, 0, stream>>>(
      x1, ffnp, ffnp + 16384L * 512, bf2, g2, b2, out);
}

// Round 9
// 515.716 us; speedup vs baseline: 1.3796x; 1.3796x over previous
//
#include <hip/hip_runtime.h>
#include <hip/hip_bf16.h>

typedef unsigned short u16;
typedef short bf16x8 __attribute__((ext_vector_type(8)));
typedef float f32x4 __attribute__((ext_vector_type(4)));

__device__ __forceinline__ float b2f(u16 u) {
  union { float f; unsigned int i; } v; v.i = ((unsigned int)u) << 16; return v.f;
}
__device__ __forceinline__ u16 f2b(float f) {
  union { float f; unsigned int i; } v; v.f = f;
  unsigned int r = v.i + 0x7fffu + ((v.i >> 16) & 1u);
  return (u16)(r >> 16);
}
__device__ __forceinline__ u16 to_b(float v) { return f2b(v); }
__device__ __forceinline__ u16 to_b(u16 v) { return v; }
__device__ __forceinline__ float to_f(float v) { return v; }
__device__ __forceinline__ float to_f(u16 v) { return b2f(v); }

// async 16B global -> LDS (dest = uniform lds base + lane*16)
__device__ __forceinline__ void gl_lds16(const u16* g, u16* l) {
  __builtin_amdgcn_global_load_lds(
      (const __attribute__((address_space(1))) unsigned int*)g,
      (__attribute__((address_space(3))) unsigned int*)l, 16, 0, 0);
}

#define VMW8()  asm volatile("s_waitcnt vmcnt(8)" ::: "memory")
#define VMW4()  asm volatile("s_waitcnt vmcnt(4)" ::: "memory")
#define VMW0()  asm volatile("s_waitcnt vmcnt(0)" ::: "memory")
#define CFENCE() asm volatile("" ::: "memory")

// ---------------- generic NT GEMM v2: double-buffered, counted-vmcnt ----------------
// Applies the session-proven lever (flash v5->v6: full-drain __syncthreads ->
// counted vmcnt = -20%) to the GEMM K-loop. Per K-step: STAGE(k+1 -> buf^1)
// stays in flight across the barrier while MFMA consumes buf; vmcnt(8)
// completes exactly stage(k), vmcnt(0) only at the last step. Compute phases
// have zero global loads (A/B frags from LDS) so the in-order-vmcnt trap
// (flash r3-r5) cannot occur. LDS 64 KB -> 2 blocks/CU. Epilogue/addressing
// byte-identical to the verified single-buffer version.
#define GSTAGE(k0v, sel)                                                     \
  {                                                                          \
    _Pragma("unroll") for (int i = 0; i < 4; i++)                            \
        gl_lds16(Ab + (long)(m0 + srow[i]) * lda + (k0v) + scol[i],          \
                 &As[sel][(w * 256 + i * 64) * 8]);                          \
    _Pragma("unroll") for (int i = 0; i < 4; i++)                            \
        gl_lds16(Bb + (long)(n0 + srow[i]) * ldb + (k0v) + scol[i],          \
                 &Bs[sel][(w * 256 + i * 64) * 8]);                          \
  }

template <bool RELU, bool ATOMIC>
__global__ __launch_bounds__(256)
void gemm_nt(const u16* __restrict__ A, const u16* __restrict__ Bt,
             const float* __restrict__ bias, void* __restrict__ Cv,
             int N, int K, int nsplit, int lda, int ldb, int ldc,
             long sA, long sB, long sC, float scale) {
  __shared__ __align__(16) u16 As[2][128 * 64];
  __shared__ __align__(16) u16 Bs[2][128 * 64];
  const int z = blockIdx.z;
  const int batch = z / nsplit, split = z - batch * nsplit;
  const int Ks = K / nsplit;
  const u16* Ab = A + (long)batch * sA + (long)split * Ks;
  const u16* Bb = Bt + (long)batch * sB + (long)split * Ks;
  const int m0 = blockIdx.y * 128, n0 = blockIdx.x * 128;
  const int t = threadIdx.x, w = t >> 6, lane = t & 63;
  const int wm = (w >> 1) * 64, wn = (w & 1) * 64;
  const int lr = lane & 15, q = lane >> 4;

  int srow[4], scol[4];
#pragma unroll
  for (int i = 0; i < 4; i++) {
    int n = w * 256 + i * 64 + lane;
    srow[i] = n >> 3;
    scol[i] = (((n & 7) ^ ((n >> 3) & 7)) * 8);
  }

  f32x4 acc[4][4];
#pragma unroll
  for (int i = 0; i < 4; i++)
#pragma unroll
    for (int j = 0; j < 4; j++) acc[i][j] = (f32x4){0.f, 0.f, 0.f, 0.f};

  const int nk = Ks >> 6;
  GSTAGE(0, 0);                    // prologue: K-step 0 in flight
  int pb = 0;

  for (int ks = 0; ks < nk; ks++) {
    if (ks + 1 < nk) {
      GSTAGE((ks + 1) << 6, pb ^ 1);
      VMW8();                      // stage(ks) landed; stage(ks+1) in flight
    } else {
      VMW0();                      // final step: nothing new in flight
    }
    __builtin_amdgcn_s_barrier();
    CFENCE();
#pragma unroll
    for (int kk = 0; kk < 2; kk++) {
      bf16x8 af[4], bfr[4];
#pragma unroll
      for (int i = 0; i < 4; i++) {
        int row = wm + i * 16 + lr;
        af[i] = *(const bf16x8*)&As[pb][row * 64 + (((kk * 4 + q) ^ (row & 7)) * 8)];
      }
#pragma unroll
      for (int j = 0; j < 4; j++) {
        int row = wn + j * 16 + lr;
        bfr[j] = *(const bf16x8*)&Bs[pb][row * 64 + (((kk * 4 + q) ^ (row & 7)) * 8)];
      }
#pragma unroll
      for (int i = 0; i < 4; i++)
#pragma unroll
        for (int j = 0; j < 4; j++)
          acc[i][j] = __builtin_amdgcn_mfma_f32_16x16x32_bf16(af[i], bfr[j], acc[i][j], 0, 0, 0);
    }
    CFENCE();
    __builtin_amdgcn_s_barrier();  // reads of buf done before stage(ks+2) overwrites
    pb ^= 1;
  }

#pragma unroll
  for (int j = 0; j < 4; j++) {
    int cg = n0 + wn + j * 16 + lr;
    float bb = (!ATOMIC && bias) ? bias[cg] : 0.0f;
#pragma unroll
    for (int i = 0; i < 4; i++) {
      int rbase = m0 + wm + i * 16 + q * 4;
#pragma unroll
      for (int r = 0; r < 4; r++) {
        float vv = acc[i][j][r] * scale;
        if (ATOMIC) {
          atomicAdd((float*)Cv + (long)batch * sC + (long)(rbase + r) * ldc + cg, vv);
        } else {
          vv += bb;
          if (RELU) vv = fmaxf(vv, 0.0f);
          ((u16*)Cv)[(long)batch * sC + (long)(rbase + r) * ldc + cg] = f2b(vv);
        }
      }
    }
  }
}

// ---------------- fused flash attention v11 (verified 234us, local optimum) ----------------
// QBLK=128, 1 block x 8 waves/CU: triple-bracketed optimum (32x32 fails on
// Q-latency exposure; QBLK=64/2-blocks fails on doubled staging intensity).
// Counted-vmcnt + Qf-before-STAGE + setprio + XCD-pinned grid.
#define STAGE_K(kvv, kcc, sel)                                               \
  {                                                                          \
    _Pragma("unroll") for (int rr = 0; rr < 4; rr++)                         \
        gl_lds16(Kbase + (long)((kvv) * 128 + srow[rr]) * 1536 +             \
                     (kcc) * 128 + scol8[rr],                                \
                 &B2[(sel)][ldsd[rr]]);                                      \
  }
#define STAGE_V(kvv, dcc, sel)                                               \
  {                                                                          \
    _Pragma("unroll") for (int rr = 0; rr < 4; rr++)                         \
        gl_lds16(Vtb + (long)((dcc) * 128 + srow[rr]) * 4096 +               \
                     (kvv) * 128 + scol8[rr],                                \
                 &B2[(sel)][ldsd[rr]]);                                      \
  }

__global__ __launch_bounds__(512, 2)
void flash_attn(const u16* __restrict__ QKV, const u16* __restrict__ Vt,
                u16* __restrict__ attp, float* __restrict__ lbp, float scl) {
  __shared__ __align__(16) u16 B2[2][128 * 128];  // 2 x 32 KB ping-pong (K/V chunks)
  __shared__ __align__(16) u16 Pb[128 * 136];     // 34 KB P stripes, wave-private
  const int flat = blockIdx.x;
  const int batch = (flat & 7) >> 1, half = flat & 1, qt = flat >> 3;
  const int t = threadIdx.x, w = t >> 6, lane = t & 63;
  const int lr = lane & 15, q = lane >> 4;
  const long rowbase = (long)batch * 4096 + qt * 128;
  const u16* Qrow  = QKV + (rowbase + w * 16 + lr) * 1536;                  // Q cols [0,512)
  const u16* Kbase = QKV + ((long)batch * 4096 + half * 2048) * 1536 + 512; // K cols [512,1024)
  const u16* Vtb   = Vt + (long)batch * 512 * 4096 + half * 2048;           // [512,4096] ld 4096
  u16* Pw = &Pb[w * (16 * 136)];

  int srow[4], scol8[4], ldsd[4];
#pragma unroll
  for (int rr = 0; rr < 4; rr++) {
    int n = rr * 512 + t;
    srow[rr] = n >> 4;
    scol8[rr] = ((n & 15) ^ ((n >> 4) & 15)) * 8;
    ldsd[rr] = (rr * 512 + w * 64) * 8;  // wave-uniform base; DMA adds lane*16B
  }

  f32x4 O[32];  // O[dc*8+j]: row=q*4+r, col=dc*128 + j*16 + lr
#pragma unroll
  for (int i = 0; i < 32; i++) O[i] = (f32x4){0.f, 0.f, 0.f, 0.f};
  float lsum[4] = {0.f, 0.f, 0.f, 0.f};

  STAGE_K(0, 0, 0);  // prologue: first chunk in flight; drained by kc=0's wait
  int par = 0;

  for (int kv = 0; kv < 16; kv++) {
    f32x4 S[8];
#pragma unroll
    for (int j = 0; j < 8; j++) S[j] = (f32x4){0.f, 0.f, 0.f, 0.f};

    // ---- QK^T: 4 chunks [128 kv x 128 k]; Qf issued BEFORE next stage ----
#pragma unroll
    for (int kc = 0; kc < 4; kc++) {
      bf16x8 Qf[4];  // older than stage(next) -> VMW4 completes them, no drain
#pragma unroll
      for (int ss = 0; ss < 4; ss++)
        Qf[ss] = *(const bf16x8*)(Qrow + kc * 128 + ss * 32 + q * 8);
      __builtin_amdgcn_sched_barrier(0);
      if (kc < 3) { STAGE_K(kv, kc + 1, par ^ 1); }
      else        { STAGE_V(kv, 0, par ^ 1); }
      VMW4();                          // stage(cur)+Qf done; stage(next) in flight
      __builtin_amdgcn_s_barrier();    // ... block-globally
      CFENCE();
      __builtin_amdgcn_s_setprio(1);
#pragma unroll
      for (int ss = 0; ss < 4; ss++)
#pragma unroll
        for (int j = 0; j < 8; j++) {
          int row = j * 16 + lr;
          bf16x8 Kf = *(const bf16x8*)&B2[par][row * 128 + (((ss * 4 + q) ^ lr) * 8)];
          S[j] = __builtin_amdgcn_mfma_f32_16x16x32_bf16(Qf[ss], Kf, S[j], 0, 0, 0);
        }
      __builtin_amdgcn_s_setprio(0);
      CFENCE();
      __builtin_amdgcn_s_barrier();    // reads done before next DMA overwrites
      par ^= 1;
    }

    // ---- P interlude: wave-private stripe in Pb, no barrier needed ----
    float psum[4] = {0.f, 0.f, 0.f, 0.f};
#pragma unroll
    for (int j = 0; j < 8; j++)
#pragma unroll
      for (int r = 0; r < 4; r++) {
        float e = __expf(S[j][r] * scl);
        psum[r] += e;
        Pw[(q * 4 + r) * 136 + j * 16 + lr] = f2b(e);
      }
#pragma unroll
    for (int r = 0; r < 4; r++) {
#pragma unroll
      for (int o = 1; o < 16; o <<= 1) psum[r] += __shfl_xor(psum[r], o);
      lsum[r] += psum[r];
    }
    bf16x8 Pf[4];  // A-frag: row=lr, k=t4*32+q*8 (same-wave write->read, lgkm-ordered)
#pragma unroll
    for (int t4 = 0; t4 < 4; t4++)
      Pf[t4] = *(const bf16x8*)&Pw[lr * 136 + t4 * 32 + q * 8];

    // ---- PV: 4 chunks [128 d x 128 kv]; true DMA/compute overlap here ----
#pragma unroll
    for (int dc = 0; dc < 4; dc++) {
      if (dc < 3) {
        STAGE_V(kv, dc + 1, par ^ 1);
        VMW4();
      } else if (kv < 15) {
        STAGE_K(kv + 1, 0, par ^ 1);
        VMW4();
      } else {
        VMW0();                        // final phase: nothing new in flight
      }
      __builtin_amdgcn_s_barrier();
      CFENCE();
      __builtin_amdgcn_s_setprio(1);
#pragma unroll
      for (int t4 = 0; t4 < 4; t4++)
#pragma unroll
        for (int j = 0; j < 8; j++) {
          int row = j * 16 + lr;
          bf16x8 Vf = *(const bf16x8*)&B2[par][row * 128 + (((t4 * 4 + q) ^ lr) * 8)];
          O[dc * 8 + j] = __builtin_amdgcn_mfma_f32_16x16x32_bf16(Pf[t4], Vf, O[dc * 8 + j], 0, 0, 0);
        }
      __builtin_amdgcn_s_setprio(0);
      CFENCE();
      __builtin_amdgcn_s_barrier();
      par ^= 1;
    }
  }

  // ---- epilogue: bf16 partial-O stores (no atomics) ----
  u16* op = attp + (long)half * 16384 * 512;
#pragma unroll
  for (int i = 0; i < 32; i++) {
    int col = (i >> 3) * 128 + (i & 7) * 16 + lr;
#pragma unroll
    for (int r = 0; r < 4; r++)
      op[(rowbase + w * 16 + q * 4 + r) * 512 + col] = f2b(O[i][r]);
  }
  if (lr == 0)
#pragma unroll
    for (int r = 0; r < 4; r++)
      lbp[(long)half * 16384 + rowbase + w * 16 + q * 4 + r] = lsum[r];
}

// ---------------- support kernels ----------------
template <typename TS>
__global__ __launch_bounds__(1024)
void transpose_b(const TS* __restrict__ src, u16* __restrict__ dst,
                 int R, int Cc, int src_ld, long sbs, long dbs) {
  __shared__ u16 tile[32][33];
  int r = blockIdx.y * 32 + threadIdx.y;
  int c = blockIdx.x * 32 + threadIdx.x;
  tile[threadIdx.y][threadIdx.x] = to_b(src[(long)blockIdx.z * sbs + (long)r * src_ld + c]);
  __syncthreads();
  int rr = blockIdx.x * 32 + threadIdx.y;
  int cc = blockIdx.y * 32 + threadIdx.x;
  dst[(long)blockIdx.z * dbs + (long)rr * R + cc] = tile[threadIdx.x][threadIdx.y];
}

__global__ __launch_bounds__(256)
void f32_to_bf16(const float* __restrict__ s, u16* __restrict__ d) {
  long i = ((long)blockIdx.x * 256 + threadIdx.x) * 8;
  float4 a0 = *(const float4*)(s + i);
  float4 a1 = *(const float4*)(s + i + 4);
  u16 tmp[8] = {f2b(a0.x), f2b(a0.y), f2b(a0.z), f2b(a0.w),
                f2b(a1.x), f2b(a1.y), f2b(a1.z), f2b(a1.w)};
  *(uint4*)(d + i) = *(uint4*)tmp;
}

// x1 = LN(x + (p0+p1)/l; g,b) -> bf16. Row 512, 1 row/wave.
__global__ __launch_bounds__(256)
void add_ln_att(const float* __restrict__ X, const u16* __restrict__ attp,
                const float* __restrict__ lbp,
                const float* __restrict__ g, const float* __restrict__ b,
                u16* __restrict__ O) {
  const int row = blockIdx.x * 4 + (threadIdx.x >> 6);
  const int lane = threadIdx.x & 63;
  const size_t base = (size_t)row * 512 + lane * 8;
  const float inv = 1.0f / (lbp[row] + lbp[16384 + row]);
  uint4 p0 = *(const uint4*)(attp + base);
  uint4 p1 = *(const uint4*)(attp + 16384L * 512 + base);
  const u16* s0 = (const u16*)&p0;
  const u16* s1 = (const u16*)&p1;
  float z[8];
  float s1a = 0.f, s2a = 0.f;
#pragma unroll
  for (int i = 0; i < 8; i++) {
    z[i] = X[base + i] + (b2f(s0[i]) + b2f(s1[i])) * inv;
    s1a += z[i]; s2a += z[i] * z[i];
  }
#pragma unroll
  for (int o = 32; o > 0; o >>= 1) { s1a += __shfl_xor(s1a, o); s2a += __shfl_xor(s2a, o); }
  const float mu = s1a * (1.0f / 512.0f);
  const float var = s2a * (1.0f / 512.0f) - mu * mu;
  const float rstd = rsqrtf(var + 1e-5f);
#pragma unroll
  for (int i = 0; i < 8; i++) {
    int c = lane * 8 + i;
    O[base + i] = f2b((z[i] - mu) * rstd * g[c] + b[c]);
  }
}

// out = LN(x1 + p0 + p1 + eb; g,b) -> fp32. Row 512, 1 row/wave.
__global__ __launch_bounds__(256)
void add_ln_ffn(const u16* __restrict__ X, const u16* __restrict__ P0,
                const u16* __restrict__ P1, const float* __restrict__ eb,
                const float* __restrict__ g, const float* __restrict__ b,
                float* __restrict__ O) {
  const int row = blockIdx.x * 4 + (threadIdx.x >> 6);
  const int lane = threadIdx.x & 63;
  const size_t base = (size_t)row * 512 + lane * 8;
  uint4 xv = *(const uint4*)(X + base);
  uint4 a0 = *(const uint4*)(P0 + base);
  uint4 a1 = *(const uint4*)(P1 + base);
  const u16* xs = (const u16*)&xv;
  const u16* s0 = (const u16*)&a0;
  const u16* s1 = (const u16*)&a1;
  float z[8];
  float s1a = 0.f, s2a = 0.f;
#pragma unroll
  for (int i = 0; i < 8; i++) {
    int c = lane * 8 + i;
    z[i] = b2f(xs[i]) + b2f(s0[i]) + b2f(s1[i]) + eb[c];
    s1a += z[i]; s2a += z[i] * z[i];
  }
#pragma unroll
  for (int o = 32; o > 0; o >>= 1) { s1a += __shfl_xor(s1a, o); s2a += __shfl_xor(s2a, o); }
  const float mu = s1a * (1.0f / 512.0f);
  const float var = s2a * (1.0f / 512.0f) - mu * mu;
  const float rstd = rsqrtf(var + 1e-5f);
#pragma unroll
  for (int i = 0; i < 8; i++) {
    int c = lane * 8 + i;
    O[base + i] = (z[i] - mu) * rstd * g[c] + b[c];
  }
}

__global__ __launch_bounds__(256)
void concat3(const float* __restrict__ a, const float* __restrict__ b,
             const float* __restrict__ c, float* __restrict__ o) {
  int i = threadIdx.x + blockIdx.x * 256;
  if (i < 512) o[i] = a[i];
  else if (i < 1024) o[i] = b[i - 512];
  else if (i < 1536) o[i] = c[i - 1024];
}

extern "C" void kernel_launch(void* const* d_in, const int* in_sizes, int n_in,
                              void* d_out, int out_size, void* d_ws, size_t ws_size,
                              hipStream_t stream) {
  const float* x   = (const float*)d_in[0];
  const float* Wq  = (const float*)d_in[1];
  const float* bq  = (const float*)d_in[2];
  const float* Wk  = (const float*)d_in[3];
  const float* bk  = (const float*)d_in[4];
  const float* Wv  = (const float*)d_in[5];
  const float* bv  = (const float*)d_in[6];
  const float* g1  = (const float*)d_in[7];
  const float* b1  = (const float*)d_in[8];
  const float* g2  = (const float*)d_in[9];
  const float* b2  = (const float*)d_in[10];
  const float* W1  = (const float*)d_in[11];
  const float* bf1 = (const float*)d_in[12];
  const float* W2  = (const float*)d_in[13];
  const float* bf2 = (const float*)d_in[14];
  float* out = (float*)d_out;

  char* ws = (char*)d_ws;
  const size_t MB = 1048576;
  u16*   QKV   = (u16*)(ws + 0);          // [16384,1536] bf16, 48 MB
  u16*   Vt    = (u16*)(ws + 48 * MB);    // [4,512,4096] bf16, 16 MB
  u16*   attp  = (u16*)(ws + 64 * MB);    // [2][16384,512] bf16 partials, 32 MB
  u16*   h     = (u16*)(ws + 64 * MB);    // [16384,2048] bf16 (after attp dead)
  float* lbp   = (float*)(ws + 128 * MB); // [2][16384] fp32 partial row sums
  u16*   x1    = (u16*)(ws + 129 * MB);   // [16384,512] bf16, 16 MB
  u16*   ffnp  = (u16*)(ws + 145 * MB);   // [2][16384,512] bf16 partials, 32 MB
  u16*   xb    = (u16*)(ws + 145 * MB);   // bf16(x), 16 MB — dead before ffnp written
  u16*   wqkvt = (u16*)(ws + 177 * MB);   // [1536,512] bf16
  u16*   w1t   = wqkvt + 1536 * 512;      // [2048,512] bf16
  u16*   w2t   = w1t + 2048 * 512;        // [512,2048] bf16
  float* bqkv  = (float*)(w2t + 512 * 2048); // [1536] fp32

  dim3 tb(32, 32);
  f32_to_bf16<<<4096, 256, 0, stream>>>(x, xb);
  transpose_b<float><<<dim3(16, 16, 1), tb, 0, stream>>>(Wq, wqkvt,              512, 512, 512, 0, 0);
  transpose_b<float><<<dim3(16, 16, 1), tb, 0, stream>>>(Wk, wqkvt + 512 * 512,  512, 512, 512, 0, 0);
  transpose_b<float><<<dim3(16, 16, 1), tb, 0, stream>>>(Wv, wqkvt + 1024 * 512, 512, 512, 512, 0, 0);
  transpose_b<float><<<dim3(64, 16, 1), tb, 0, stream>>>(W1, w1t, 512, 2048, 2048, 0, 0);
  transpose_b<float><<<dim3(16, 64, 1), tb, 0, stream>>>(W2, w2t, 2048, 512, 512, 0, 0);
  concat3<<<6, 256, 0, stream>>>(bq, bk, bv, bqkv);

  // Fused QKV projection
  gemm_nt<false, false><<<dim3(12, 128, 1), 256, 0, stream>>>(
      xb, wqkvt, bqkv, QKV, 1536, 512, 1, 512, 512, 1536, 0, 0, 0, 1.0f);

  // V^T per batch
  transpose_b<u16><<<dim3(16, 128, 4), tb, 0, stream>>>(
      QKV + 1024, Vt, 4096, 512, 1536, 4096L * 1536, 512L * 4096);

  const float scl = 0.044194173824159216f;  // 1/sqrt(512)
  // Fused attention: QBLK=128, v11 structure (verified 234us)
  flash_attn<<<dim3(256, 1, 1), 512, 0, stream>>>(QKV, Vt, attp, lbp, scl);

  // x1 = LN(x + (p0+p1)/l)
  add_ln_att<<<4096, 256, 0, stream>>>(x, attp, lbp, g1, b1, x1);
  // h = relu(x1 W1 + bf1)   (h overwrites dead attp region)
  gemm_nt<true, false><<<dim3(16, 128, 1), 256, 0, stream>>>(
      x1, w1t, bf1, h, 2048, 512, 1, 512, 512, 2048, 0, 0, 0, 1.0f);
  // ffnp[z] = h[:, z*1024:(z+1)*1024] W2[z*1024:(z+1)*1024, :] (bf16 partials)
  gemm_nt<false, false><<<dim3(4, 128, 2), 256, 0, stream>>>(
      h, w2t, nullptr, ffnp, 512, 1024, 1, 2048, 2048, 512,
      1024, 1024, 16384L * 512, 1.0f);
  // out = LN(x1 + p0 + p1 + bf2) -> fp32
  add_ln_ffn<<<4096, 256, 0, stream>>>(
      x1, ffnp, ffnp + 16384L * 512, bf2, g2, b2, out);
}

// Round 10
// 507.520 us; speedup vs baseline: 1.4018x; 1.0161x over previous
//
#include <hip/hip_runtime.h>
#include <hip/hip_bf16.h>

typedef unsigned short u16;
typedef short bf16x8 __attribute__((ext_vector_type(8)));
typedef float f32x4 __attribute__((ext_vector_type(4)));

__device__ __forceinline__ float b2f(u16 u) {
  union { float f; unsigned int i; } v; v.i = ((unsigned int)u) << 16; return v.f;
}
__device__ __forceinline__ u16 f2b(float f) {
  union { float f; unsigned int i; } v; v.f = f;
  unsigned int r = v.i + 0x7fffu + ((v.i >> 16) & 1u);
  return (u16)(r >> 16);
}
__device__ __forceinline__ u16 to_b(float v) { return f2b(v); }
__device__ __forceinline__ u16 to_b(u16 v) { return v; }
__device__ __forceinline__ float to_f(float v) { return v; }
__device__ __forceinline__ float to_f(u16 v) { return b2f(v); }

// async 16B global -> LDS (dest = uniform lds base + lane*16)
__device__ __forceinline__ void gl_lds16(const u16* g, u16* l) {
  __builtin_amdgcn_global_load_lds(
      (const __attribute__((address_space(1))) unsigned int*)g,
      (__attribute__((address_space(3))) unsigned int*)l, 16, 0, 0);
}

#define VMW4()  asm volatile("s_waitcnt vmcnt(4)" ::: "memory")
#define VMW0()  asm volatile("s_waitcnt vmcnt(0)" ::: "memory")
#define CFENCE() asm volatile("" ::: "memory")

// ---------------- generic NT GEMM (single-buffer, verified) + XCD swizzle ----------------
// Round-9 post-mortem: dbuf was neutral (64KB LDS halved residency, canceling
// the pipeline gain) -> reverted to the verified single-buffer (32KB, ~5
// blocks/CU). NEW: XCD-aware block swizzle (T1). Default mapping spreads the
// blocks sharing an A row-panel round-robin over 8 XCDs -> every XCD re-fetches
// every A panel from L3 and the whole B matrix. Swizzle gives each XCD a
// contiguous 16-panel M-chunk: per-XCD working set = A 2MB + B <=2MB <= 4MB L2
// -> staging becomes L2-hits. Bijective since gridDim.y==128 (mod 8 == 0) for
// all three GEMM shapes. Pure index remap; layouts/protocol unchanged.
template <bool RELU, bool ATOMIC>
__global__ __launch_bounds__(256)
void gemm_nt(const u16* __restrict__ A, const u16* __restrict__ Bt,
             const float* __restrict__ bias, void* __restrict__ Cv,
             int N, int K, int nsplit, int lda, int ldb, int ldc,
             long sA, long sB, long sC, float scale) {
  __shared__ __align__(16) u16 As[128 * 64];
  __shared__ __align__(16) u16 Bs[128 * 64];
  const int z = blockIdx.z;
  const int batch = z / nsplit, split = z - batch * nsplit;
  const int Ks = K / nsplit;
  const u16* Ab = A + (long)batch * sA + (long)split * Ks;
  const u16* Bb = Bt + (long)batch * sB + (long)split * Ks;
  // XCD swizzle: xcd = flat%8 gets contiguous M-panel chunk
  const int f = blockIdx.x + gridDim.x * blockIdx.y;
  const int xcd = f & 7, idx = f >> 3;
  const int bx = idx % gridDim.x;
  const int by = xcd * (gridDim.y >> 3) + idx / gridDim.x;
  const int m0 = by * 128, n0 = bx * 128;
  const int t = threadIdx.x, w = t >> 6, lane = t & 63;
  const int wm = (w >> 1) * 64, wn = (w & 1) * 64;
  const int lr = lane & 15, q = lane >> 4;

  int srow[4], scol[4];
#pragma unroll
  for (int i = 0; i < 4; i++) {
    int n = w * 256 + i * 64 + lane;
    srow[i] = n >> 3;
    scol[i] = (((n & 7) ^ ((n >> 3) & 7)) * 8);
  }

  f32x4 acc[4][4];
#pragma unroll
  for (int i = 0; i < 4; i++)
#pragma unroll
    for (int j = 0; j < 4; j++) acc[i][j] = (f32x4){0.f, 0.f, 0.f, 0.f};

  for (int k0 = 0; k0 < Ks; k0 += 64) {
#pragma unroll
    for (int i = 0; i < 4; i++)
      gl_lds16(Ab + (long)(m0 + srow[i]) * lda + k0 + scol[i], &As[(w * 256 + i * 64) * 8]);
#pragma unroll
    for (int i = 0; i < 4; i++)
      gl_lds16(Bb + (long)(n0 + srow[i]) * ldb + k0 + scol[i], &Bs[(w * 256 + i * 64) * 8]);
    __syncthreads();
#pragma unroll
    for (int kk = 0; kk < 2; kk++) {
      bf16x8 af[4], bfr[4];
#pragma unroll
      for (int i = 0; i < 4; i++) {
        int row = wm + i * 16 + lr;
        af[i] = *(const bf16x8*)&As[row * 64 + (((kk * 4 + q) ^ (row & 7)) * 8)];
      }
#pragma unroll
      for (int j = 0; j < 4; j++) {
        int row = wn + j * 16 + lr;
        bfr[j] = *(const bf16x8*)&Bs[row * 64 + (((kk * 4 + q) ^ (row & 7)) * 8)];
      }
#pragma unroll
      for (int i = 0; i < 4; i++)
#pragma unroll
        for (int j = 0; j < 4; j++)
          acc[i][j] = __builtin_amdgcn_mfma_f32_16x16x32_bf16(af[i], bfr[j], acc[i][j], 0, 0, 0);
    }
    __syncthreads();
  }

#pragma unroll
  for (int j = 0; j < 4; j++) {
    int cg = n0 + wn + j * 16 + lr;
    float bb = (!ATOMIC && bias) ? bias[cg] : 0.0f;
#pragma unroll
    for (int i = 0; i < 4; i++) {
      int rbase = m0 + wm + i * 16 + q * 4;
#pragma unroll
      for (int r = 0; r < 4; r++) {
        float vv = acc[i][j][r] * scale;
        if (ATOMIC) {
          atomicAdd((float*)Cv + (long)batch * sC + (long)(rbase + r) * ldc + cg, vv);
        } else {
          vv += bb;
          if (RELU) vv = fmaxf(vv, 0.0f);
          ((u16*)Cv)[(long)batch * sC + (long)(rbase + r) * ldc + cg] = f2b(vv);
        }
      }
    }
  }
}

// ---------------- fused flash attention v11 (verified 231us, local optimum) ----------------
// QBLK=128, 1 block x 8 waves/CU: triple-bracketed optimum (32x32 fails on
// Q-latency exposure; QBLK=64/2-blocks fails on doubled staging intensity).
// Counted-vmcnt + Qf-before-STAGE + setprio + XCD-pinned grid.
#define STAGE_K(kvv, kcc, sel)                                               \
  {                                                                          \
    _Pragma("unroll") for (int rr = 0; rr < 4; rr++)                         \
        gl_lds16(Kbase + (long)((kvv) * 128 + srow[rr]) * 1536 +             \
                     (kcc) * 128 + scol8[rr],                                \
                 &B2[(sel)][ldsd[rr]]);                                      \
  }
#define STAGE_V(kvv, dcc, sel)                                               \
  {                                                                          \
    _Pragma("unroll") for (int rr = 0; rr < 4; rr++)                         \
        gl_lds16(Vtb + (long)((dcc) * 128 + srow[rr]) * 4096 +               \
                     (kvv) * 128 + scol8[rr],                                \
                 &B2[(sel)][ldsd[rr]]);                                      \
  }

__global__ __launch_bounds__(512, 2)
void flash_attn(const u16* __restrict__ QKV, const u16* __restrict__ Vt,
                u16* __restrict__ attp, float* __restrict__ lbp, float scl) {
  __shared__ __align__(16) u16 B2[2][128 * 128];  // 2 x 32 KB ping-pong (K/V chunks)
  __shared__ __align__(16) u16 Pb[128 * 136];     // 34 KB P stripes, wave-private
  const int flat = blockIdx.x;
  const int batch = (flat & 7) >> 1, half = flat & 1, qt = flat >> 3;
  const int t = threadIdx.x, w = t >> 6, lane = t & 63;
  const int lr = lane & 15, q = lane >> 4;
  const long rowbase = (long)batch * 4096 + qt * 128;
  const u16* Qrow  = QKV + (rowbase + w * 16 + lr) * 1536;                  // Q cols [0,512)
  const u16* Kbase = QKV + ((long)batch * 4096 + half * 2048) * 1536 + 512; // K cols [512,1024)
  const u16* Vtb   = Vt + (long)batch * 512 * 4096 + half * 2048;           // [512,4096] ld 4096
  u16* Pw = &Pb[w * (16 * 136)];

  int srow[4], scol8[4], ldsd[4];
#pragma unroll
  for (int rr = 0; rr < 4; rr++) {
    int n = rr * 512 + t;
    srow[rr] = n >> 4;
    scol8[rr] = ((n & 15) ^ ((n >> 4) & 15)) * 8;
    ldsd[rr] = (rr * 512 + w * 64) * 8;  // wave-uniform base; DMA adds lane*16B
  }

  f32x4 O[32];  // O[dc*8+j]: row=q*4+r, col=dc*128 + j*16 + lr
#pragma unroll
  for (int i = 0; i < 32; i++) O[i] = (f32x4){0.f, 0.f, 0.f, 0.f};
  float lsum[4] = {0.f, 0.f, 0.f, 0.f};

  STAGE_K(0, 0, 0);  // prologue: first chunk in flight; drained by kc=0's wait
  int par = 0;

  for (int kv = 0; kv < 16; kv++) {
    f32x4 S[8];
#pragma unroll
    for (int j = 0; j < 8; j++) S[j] = (f32x4){0.f, 0.f, 0.f, 0.f};

    // ---- QK^T: 4 chunks [128 kv x 128 k]; Qf issued BEFORE next stage ----
#pragma unroll
    for (int kc = 0; kc < 4; kc++) {
      bf16x8 Qf[4];  // older than stage(next) -> VMW4 completes them, no drain
#pragma unroll
      for (int ss = 0; ss < 4; ss++)
        Qf[ss] = *(const bf16x8*)(Qrow + kc * 128 + ss * 32 + q * 8);
      __builtin_amdgcn_sched_barrier(0);
      if (kc < 3) { STAGE_K(kv, kc + 1, par ^ 1); }
      else        { STAGE_V(kv, 0, par ^ 1); }
      VMW4();                          // stage(cur)+Qf done; stage(next) in flight
      __builtin_amdgcn_s_barrier();    // ... block-globally
      CFENCE();
      __builtin_amdgcn_s_setprio(1);
#pragma unroll
      for (int ss = 0; ss < 4; ss++)
#pragma unroll
        for (int j = 0; j < 8; j++) {
          int row = j * 16 + lr;
          bf16x8 Kf = *(const bf16x8*)&B2[par][row * 128 + (((ss * 4 + q) ^ lr) * 8)];
          S[j] = __builtin_amdgcn_mfma_f32_16x16x32_bf16(Qf[ss], Kf, S[j], 0, 0, 0);
        }
      __builtin_amdgcn_s_setprio(0);
      CFENCE();
      __builtin_amdgcn_s_barrier();    // reads done before next DMA overwrites
      par ^= 1;
    }

    // ---- P interlude: wave-private stripe in Pb, no barrier needed ----
    float psum[4] = {0.f, 0.f, 0.f, 0.f};
#pragma unroll
    for (int j = 0; j < 8; j++)
#pragma unroll
      for (int r = 0; r < 4; r++) {
        float e = __expf(S[j][r] * scl);
        psum[r] += e;
        Pw[(q * 4 + r) * 136 + j * 16 + lr] = f2b(e);
      }
#pragma unroll
    for (int r = 0; r < 4; r++) {
#pragma unroll
      for (int o = 1; o < 16; o <<= 1) psum[r] += __shfl_xor(psum[r], o);
      lsum[r] += psum[r];
    }
    bf16x8 Pf[4];  // A-frag: row=lr, k=t4*32+q*8 (same-wave write->read, lgkm-ordered)
#pragma unroll
    for (int t4 = 0; t4 < 4; t4++)
      Pf[t4] = *(const bf16x8*)&Pw[lr * 136 + t4 * 32 + q * 8];

    // ---- PV: 4 chunks [128 d x 128 kv]; true DMA/compute overlap here ----
#pragma unroll
    for (int dc = 0; dc < 4; dc++) {
      if (dc < 3) {
        STAGE_V(kv, dc + 1, par ^ 1);
        VMW4();
      } else if (kv < 15) {
        STAGE_K(kv + 1, 0, par ^ 1);
        VMW4();
      } else {
        VMW0();                        // final phase: nothing new in flight
      }
      __builtin_amdgcn_s_barrier();
      CFENCE();
      __builtin_amdgcn_s_setprio(1);
#pragma unroll
      for (int t4 = 0; t4 < 4; t4++)
#pragma unroll
        for (int j = 0; j < 8; j++) {
          int row = j * 16 + lr;
          bf16x8 Vf = *(const bf16x8*)&B2[par][row * 128 + (((t4 * 4 + q) ^ lr) * 8)];
          O[dc * 8 + j] = __builtin_amdgcn_mfma_f32_16x16x32_bf16(Pf[t4], Vf, O[dc * 8 + j], 0, 0, 0);
        }
      __builtin_amdgcn_s_setprio(0);
      CFENCE();
      __builtin_amdgcn_s_barrier();
      par ^= 1;
    }
  }

  // ---- epilogue: bf16 partial-O stores (no atomics) ----
  u16* op = attp + (long)half * 16384 * 512;
#pragma unroll
  for (int i = 0; i < 32; i++) {
    int col = (i >> 3) * 128 + (i & 7) * 16 + lr;
#pragma unroll
    for (int r = 0; r < 4; r++)
      op[(rowbase + w * 16 + q * 4 + r) * 512 + col] = f2b(O[i][r]);
  }
  if (lr == 0)
#pragma unroll
    for (int r = 0; r < 4; r++)
      lbp[(long)half * 16384 + rowbase + w * 16 + q * 4 + r] = lsum[r];
}

// ---------------- support kernels ----------------
template <typename TS>
__global__ __launch_bounds__(1024)
void transpose_b(const TS* __restrict__ src, u16* __restrict__ dst,
                 int R, int Cc, int src_ld, long sbs, long dbs) {
  __shared__ u16 tile[32][33];
  int r = blockIdx.y * 32 + threadIdx.y;
  int c = blockIdx.x * 32 + threadIdx.x;
  tile[threadIdx.y][threadIdx.x] = to_b(src[(long)blockIdx.z * sbs + (long)r * src_ld + c]);
  __syncthreads();
  int rr = blockIdx.x * 32 + threadIdx.y;
  int cc = blockIdx.y * 32 + threadIdx.x;
  dst[(long)blockIdx.z * dbs + (long)rr * R + cc] = tile[threadIdx.x][threadIdx.y];
}

__global__ __launch_bounds__(256)
void f32_to_bf16(const float* __restrict__ s, u16* __restrict__ d) {
  long i = ((long)blockIdx.x * 256 + threadIdx.x) * 8;
  float4 a0 = *(const float4*)(s + i);
  float4 a1 = *(const float4*)(s + i + 4);
  u16 tmp[8] = {f2b(a0.x), f2b(a0.y), f2b(a0.z), f2b(a0.w),
                f2b(a1.x), f2b(a1.y), f2b(a1.z), f2b(a1.w)};
  *(uint4*)(d + i) = *(uint4*)tmp;
}

// x1 = LN(x + (p0+p1)/l; g,b) -> bf16. Row 512, 1 row/wave.
__global__ __launch_bounds__(256)
void add_ln_att(const float* __restrict__ X, const u16* __restrict__ attp,
                const float* __restrict__ lbp,
                const float* __restrict__ g, const float* __restrict__ b,
                u16* __restrict__ O) {
  const int row = blockIdx.x * 4 + (threadIdx.x >> 6);
  const int lane = threadIdx.x & 63;
  const size_t base = (size_t)row * 512 + lane * 8;
  const float inv = 1.0f / (lbp[row] + lbp[16384 + row]);
  uint4 p0 = *(const uint4*)(attp + base);
  uint4 p1 = *(const uint4*)(attp + 16384L * 512 + base);
  const u16* s0 = (const u16*)&p0;
  const u16* s1 = (const u16*)&p1;
  float z[8];
  float s1a = 0.f, s2a = 0.f;
#pragma unroll
  for (int i = 0; i < 8; i++) {
    z[i] = X[base + i] + (b2f(s0[i]) + b2f(s1[i])) * inv;
    s1a += z[i]; s2a += z[i] * z[i];
  }
#pragma unroll
  for (int o = 32; o > 0; o >>= 1) { s1a += __shfl_xor(s1a, o); s2a += __shfl_xor(s2a, o); }
  const float mu = s1a * (1.0f / 512.0f);
  const float var = s2a * (1.0f / 512.0f) - mu * mu;
  const float rstd = rsqrtf(var + 1e-5f);
#pragma unroll
  for (int i = 0; i < 8; i++) {
    int c = lane * 8 + i;
    O[base + i] = f2b((z[i] - mu) * rstd * g[c] + b[c]);
  }
}

// out = LN(x1 + p0 + p1 + eb; g,b) -> fp32. Row 512, 1 row/wave.
__global__ __launch_bounds__(256)
void add_ln_ffn(const u16* __restrict__ X, const u16* __restrict__ P0,
                const u16* __restrict__ P1, const float* __restrict__ eb,
                const float* __restrict__ g, const float* __restrict__ b,
                float* __restrict__ O) {
  const int row = blockIdx.x * 4 + (threadIdx.x >> 6);
  const int lane = threadIdx.x & 63;
  const size_t base = (size_t)row * 512 + lane * 8;
  uint4 xv = *(const uint4*)(X + base);
  uint4 a0 = *(const uint4*)(P0 + base);
  uint4 a1 = *(const uint4*)(P1 + base);
  const u16* xs = (const u16*)&xv;
  const u16* s0 = (const u16*)&a0;
  const u16* s1 = (const u16*)&a1;
  float z[8];
  float s1a = 0.f, s2a = 0.f;
#pragma unroll
  for (int i = 0; i < 8; i++) {
    int c = lane * 8 + i;
    z[i] = b2f(xs[i]) + b2f(s0[i]) + b2f(s1[i]) + eb[c];
    s1a += z[i]; s2a += z[i] * z[i];
  }
#pragma unroll
  for (int o = 32; o > 0; o >>= 1) { s1a += __shfl_xor(s1a, o); s2a += __shfl_xor(s2a, o); }
  const float mu = s1a * (1.0f / 512.0f);
  const float var = s2a * (1.0f / 512.0f) - mu * mu;
  const float rstd = rsqrtf(var + 1e-5f);
#pragma unroll
  for (int i = 0; i < 8; i++) {
    int c = lane * 8 + i;
    O[base + i] = (z[i] - mu) * rstd * g[c] + b[c];
  }
}

__global__ __launch_bounds__(256)
void concat3(const float* __restrict__ a, const float* __restrict__ b,
             const float* __restrict__ c, float* __restrict__ o) {
  int i = threadIdx.x + blockIdx.x * 256;
  if (i < 512) o[i] = a[i];
  else if (i < 1024) o[i] = b[i - 512];
  else if (i < 1536) o[i] = c[i - 1024];
}

extern "C" void kernel_launch(void* const* d_in, const int* in_sizes, int n_in,
                              void* d_out, int out_size, void* d_ws, size_t ws_size,
                              hipStream_t stream) {
  const float* x   = (const float*)d_in[0];
  const float* Wq  = (const float*)d_in[1];
  const float* bq  = (const float*)d_in[2];
  const float* Wk  = (const float*)d_in[3];
  const float* bk  = (const float*)d_in[4];
  const float* Wv  = (const float*)d_in[5];
  const float* bv  = (const float*)d_in[6];
  const float* g1  = (const float*)d_in[7];
  const float* b1  = (const float*)d_in[8];
  const float* g2  = (const float*)d_in[9];
  const float* b2  = (const float*)d_in[10];
  const float* W1  = (const float*)d_in[11];
  const float* bf1 = (const float*)d_in[12];
  const float* W2  = (const float*)d_in[13];
  const float* bf2 = (const float*)d_in[14];
  float* out = (float*)d_out;

  char* ws = (char*)d_ws;
  const size_t MB = 1048576;
  u16*   QKV   = (u16*)(ws + 0);          // [16384,1536] bf16, 48 MB
  u16*   Vt    = (u16*)(ws + 48 * MB);    // [4,512,4096] bf16, 16 MB
  u16*   attp  = (u16*)(ws + 64 * MB);    // [2][16384,512] bf16 partials, 32 MB
  u16*   h     = (u16*)(ws + 64 * MB);    // [16384,2048] bf16 (after attp dead)
  float* lbp   = (float*)(ws + 128 * MB); // [2][16384] fp32 partial row sums
  u16*   x1    = (u16*)(ws + 129 * MB);   // [16384,512] bf16, 16 MB
  u16*   ffnp  = (u16*)(ws + 145 * MB);   // [2][16384,512] bf16 partials, 32 MB
  u16*   xb    = (u16*)(ws + 145 * MB);   // bf16(x), 16 MB — dead before ffnp written
  u16*   wqkvt = (u16*)(ws + 177 * MB);   // [1536,512] bf16
  u16*   w1t   = wqkvt + 1536 * 512;      // [2048,512] bf16
  u16*   w2t   = w1t + 2048 * 512;        // [512,2048] bf16
  float* bqkv  = (float*)(w2t + 512 * 2048); // [1536] fp32

  dim3 tb(32, 32);
  f32_to_bf16<<<4096, 256, 0, stream>>>(x, xb);
  transpose_b<float><<<dim3(16, 16, 1), tb, 0, stream>>>(Wq, wqkvt,              512, 512, 512, 0, 0);
  transpose_b<float><<<dim3(16, 16, 1), tb, 0, stream>>>(Wk, wqkvt + 512 * 512,  512, 512, 512, 0, 0);
  transpose_b<float><<<dim3(16, 16, 1), tb, 0, stream>>>(Wv, wqkvt + 1024 * 512, 512, 512, 512, 0, 0);
  transpose_b<float><<<dim3(64, 16, 1), tb, 0, stream>>>(W1, w1t, 512, 2048, 2048, 0, 0);
  transpose_b<float><<<dim3(16, 64, 1), tb, 0, stream>>>(W2, w2t, 2048, 512, 512, 0, 0);
  concat3<<<6, 256, 0, stream>>>(bq, bk, bv, bqkv);

  // Fused QKV projection
  gemm_nt<false, false><<<dim3(12, 128, 1), 256, 0, stream>>>(
      xb, wqkvt, bqkv, QKV, 1536, 512, 1, 512, 512, 1536, 0, 0, 0, 1.0f);

  // V^T per batch
  transpose_b<u16><<<dim3(16, 128, 4), tb, 0, stream>>>(
      QKV + 1024, Vt, 4096, 512, 1536, 4096L * 1536, 512L * 4096);

  const float scl = 0.044194173824159216f;  // 1/sqrt(512)
  // Fused attention: QBLK=128, v11 structure (verified 231us)
  flash_attn<<<dim3(256, 1, 1), 512, 0, stream>>>(QKV, Vt, attp, lbp, scl);

  // x1 = LN(x + (p0+p1)/l)
  add_ln_att<<<4096, 256, 0, stream>>>(x, attp, lbp, g1, b1, x1);
  // h = relu(x1 W1 + bf1)   (h overwrites dead attp region)
  gemm_nt<true, false><<<dim3(16, 128, 1), 256, 0, stream>>>(
      x1, w1t, bf1, h, 2048, 512, 1, 512, 512, 2048, 0, 0, 0, 1.0f);
  // ffnp[z] = h[:, z*1024:(z+1)*1024] W2[z*1024:(z+1)*1024, :] (bf16 partials)
  gemm_nt<false, false><<<dim3(4, 128, 2), 256, 0, stream>>>(
      h, w2t, nullptr, ffnp, 512, 1024, 1, 2048, 2048, 512,
      1024, 1024, 16384L * 512, 1.0f);
  // out = LN(x1 + p0 + p1 + bf2) -> fp32
  add_ln_ffn<<<4096, 256, 0, stream>>>(
      x1, ffnp, ffnp + 16384L * 512, bf2, g2, b2, out);
}

// Round 11
// 502.550 us; speedup vs baseline: 1.4157x; 1.0099x over previous
//
#include <hip/hip_runtime.h>
#include <hip/hip_bf16.h>

typedef unsigned short u16;
typedef short bf16x8 __attribute__((ext_vector_type(8)));
typedef float f32x4 __attribute__((ext_vector_type(4)));

__device__ __forceinline__ float b2f(u16 u) {
  union { float f; unsigned int i; } v; v.i = ((unsigned int)u) << 16; return v.f;
}
__device__ __forceinline__ u16 f2b(float f) {
  union { float f; unsigned int i; } v; v.f = f;
  unsigned int r = v.i + 0x7fffu + ((v.i >> 16) & 1u);
  return (u16)(r >> 16);
}
__device__ __forceinline__ u16 to_b(float v) { return f2b(v); }
__device__ __forceinline__ u16 to_b(u16 v) { return v; }

// async 16B global -> LDS (dest = uniform lds base + lane*16)
__device__ __forceinline__ void gl_lds16(const u16* g, u16* l) {
  __builtin_amdgcn_global_load_lds(
      (const __attribute__((address_space(1))) unsigned int*)g,
      (__attribute__((address_space(3))) unsigned int*)l, 16, 0, 0);
}

#define VMW4()  asm volatile("s_waitcnt vmcnt(4)" ::: "memory")
#define VMW0()  asm volatile("s_waitcnt vmcnt(0)" ::: "memory")
#define CFENCE() asm volatile("" ::: "memory")

// ---------------- generic NT GEMM (single-buffer, verified) + XCD swizzle ----------------
template <bool RELU, bool ATOMIC>
__global__ __launch_bounds__(256)
void gemm_nt(const u16* __restrict__ A, const u16* __restrict__ Bt,
             const float* __restrict__ bias, void* __restrict__ Cv,
             int N, int K, int nsplit, int lda, int ldb, int ldc,
             long sA, long sB, long sC, float scale) {
  __shared__ __align__(16) u16 As[128 * 64];
  __shared__ __align__(16) u16 Bs[128 * 64];
  const int z = blockIdx.z;
  const int batch = z / nsplit, split = z - batch * nsplit;
  const int Ks = K / nsplit;
  const u16* Ab = A + (long)batch * sA + (long)split * Ks;
  const u16* Bb = Bt + (long)batch * sB + (long)split * Ks;
  // XCD swizzle: xcd = flat%8 gets contiguous M-panel chunk (bijective: gridDim.y%8==0)
  const int f = blockIdx.x + gridDim.x * blockIdx.y;
  const int xcd = f & 7, idx = f >> 3;
  const int bx = idx % gridDim.x;
  const int by = xcd * (gridDim.y >> 3) + idx / gridDim.x;
  const int m0 = by * 128, n0 = bx * 128;
  const int t = threadIdx.x, w = t >> 6, lane = t & 63;
  const int wm = (w >> 1) * 64, wn = (w & 1) * 64;
  const int lr = lane & 15, q = lane >> 4;

  int srow[4], scol[4];
#pragma unroll
  for (int i = 0; i < 4; i++) {
    int n = w * 256 + i * 64 + lane;
    srow[i] = n >> 3;
    scol[i] = (((n & 7) ^ ((n >> 3) & 7)) * 8);
  }

  f32x4 acc[4][4];
#pragma unroll
  for (int i = 0; i < 4; i++)
#pragma unroll
    for (int j = 0; j < 4; j++) acc[i][j] = (f32x4){0.f, 0.f, 0.f, 0.f};

  for (int k0 = 0; k0 < Ks; k0 += 64) {
#pragma unroll
    for (int i = 0; i < 4; i++)
      gl_lds16(Ab + (long)(m0 + srow[i]) * lda + k0 + scol[i], &As[(w * 256 + i * 64) * 8]);
#pragma unroll
    for (int i = 0; i < 4; i++)
      gl_lds16(Bb + (long)(n0 + srow[i]) * ldb + k0 + scol[i], &Bs[(w * 256 + i * 64) * 8]);
    __syncthreads();
#pragma unroll
    for (int kk = 0; kk < 2; kk++) {
      bf16x8 af[4], bfr[4];
#pragma unroll
      for (int i = 0; i < 4; i++) {
        int row = wm + i * 16 + lr;
        af[i] = *(const bf16x8*)&As[row * 64 + (((kk * 4 + q) ^ (row & 7)) * 8)];
      }
#pragma unroll
      for (int j = 0; j < 4; j++) {
        int row = wn + j * 16 + lr;
        bfr[j] = *(const bf16x8*)&Bs[row * 64 + (((kk * 4 + q) ^ (row & 7)) * 8)];
      }
#pragma unroll
      for (int i = 0; i < 4; i++)
#pragma unroll
        for (int j = 0; j < 4; j++)
          acc[i][j] = __builtin_amdgcn_mfma_f32_16x16x32_bf16(af[i], bfr[j], acc[i][j], 0, 0, 0);
    }
    __syncthreads();
  }

#pragma unroll
  for (int j = 0; j < 4; j++) {
    int cg = n0 + wn + j * 16 + lr;
    float bb = (!ATOMIC && bias) ? bias[cg] : 0.0f;
#pragma unroll
    for (int i = 0; i < 4; i++) {
      int rbase = m0 + wm + i * 16 + q * 4;
#pragma unroll
      for (int r = 0; r < 4; r++) {
        float vv = acc[i][j][r] * scale;
        if (ATOMIC) {
          atomicAdd((float*)Cv + (long)batch * sC + (long)(rbase + r) * ldc + cg, vv);
        } else {
          vv += bb;
          if (RELU) vv = fmaxf(vv, 0.0f);
          ((u16*)Cv)[(long)batch * sC + (long)(rbase + r) * ldc + cg] = f2b(vv);
        }
      }
    }
  }
}

// ---------------- fused flash attention v11 (verified 231us, local optimum) ----------------
#define STAGE_K(kvv, kcc, sel)                                               \
  {                                                                          \
    _Pragma("unroll") for (int rr = 0; rr < 4; rr++)                         \
        gl_lds16(Kbase + (long)((kvv) * 128 + srow[rr]) * 1536 +             \
                     (kcc) * 128 + scol8[rr],                                \
                 &B2[(sel)][ldsd[rr]]);                                      \
  }
#define STAGE_V(kvv, dcc, sel)                                               \
  {                                                                          \
    _Pragma("unroll") for (int rr = 0; rr < 4; rr++)                         \
        gl_lds16(Vtb + (long)((dcc) * 128 + srow[rr]) * 4096 +               \
                     (kvv) * 128 + scol8[rr],                                \
                 &B2[(sel)][ldsd[rr]]);                                      \
  }

__global__ __launch_bounds__(512, 2)
void flash_attn(const u16* __restrict__ QKV, const u16* __restrict__ Vt,
                u16* __restrict__ attp, float* __restrict__ lbp, float scl) {
  __shared__ __align__(16) u16 B2[2][128 * 128];  // 2 x 32 KB ping-pong (K/V chunks)
  __shared__ __align__(16) u16 Pb[128 * 136];     // 34 KB P stripes, wave-private
  const int flat = blockIdx.x;
  const int batch = (flat & 7) >> 1, half = flat & 1, qt = flat >> 3;
  const int t = threadIdx.x, w = t >> 6, lane = t & 63;
  const int lr = lane & 15, q = lane >> 4;
  const long rowbase = (long)batch * 4096 + qt * 128;
  const u16* Qrow  = QKV + (rowbase + w * 16 + lr) * 1536;                  // Q cols [0,512)
  const u16* Kbase = QKV + ((long)batch * 4096 + half * 2048) * 1536 + 512; // K cols [512,1024)
  const u16* Vtb   = Vt + (long)batch * 512 * 4096 + half * 2048;           // [512,4096] ld 4096
  u16* Pw = &Pb[w * (16 * 136)];

  int srow[4], scol8[4], ldsd[4];
#pragma unroll
  for (int rr = 0; rr < 4; rr++) {
    int n = rr * 512 + t;
    srow[rr] = n >> 4;
    scol8[rr] = ((n & 15) ^ ((n >> 4) & 15)) * 8;
    ldsd[rr] = (rr * 512 + w * 64) * 8;  // wave-uniform base; DMA adds lane*16B
  }

  f32x4 O[32];  // O[dc*8+j]: row=q*4+r, col=dc*128 + j*16 + lr
#pragma unroll
  for (int i = 0; i < 32; i++) O[i] = (f32x4){0.f, 0.f, 0.f, 0.f};
  float lsum[4] = {0.f, 0.f, 0.f, 0.f};

  STAGE_K(0, 0, 0);  // prologue: first chunk in flight; drained by kc=0's wait
  int par = 0;

  for (int kv = 0; kv < 16; kv++) {
    f32x4 S[8];
#pragma unroll
    for (int j = 0; j < 8; j++) S[j] = (f32x4){0.f, 0.f, 0.f, 0.f};

    // ---- QK^T: 4 chunks [128 kv x 128 k]; Qf issued BEFORE next stage ----
#pragma unroll
    for (int kc = 0; kc < 4; kc++) {
      bf16x8 Qf[4];  // older than stage(next) -> VMW4 completes them, no drain
#pragma unroll
      for (int ss = 0; ss < 4; ss++)
        Qf[ss] = *(const bf16x8*)(Qrow + kc * 128 + ss * 32 + q * 8);
      __builtin_amdgcn_sched_barrier(0);
      if (kc < 3) { STAGE_K(kv, kc + 1, par ^ 1); }
      else        { STAGE_V(kv, 0, par ^ 1); }
      VMW4();                          // stage(cur)+Qf done; stage(next) in flight
      __builtin_amdgcn_s_barrier();    // ... block-globally
      CFENCE();
      __builtin_amdgcn_s_setprio(1);
#pragma unroll
      for (int ss = 0; ss < 4; ss++)
#pragma unroll
        for (int j = 0; j < 8; j++) {
          int row = j * 16 + lr;
          bf16x8 Kf = *(const bf16x8*)&B2[par][row * 128 + (((ss * 4 + q) ^ lr) * 8)];
          S[j] = __builtin_amdgcn_mfma_f32_16x16x32_bf16(Qf[ss], Kf, S[j], 0, 0, 0);
        }
      __builtin_amdgcn_s_setprio(0);
      CFENCE();
      __builtin_amdgcn_s_barrier();    // reads done before next DMA overwrites
      par ^= 1;
    }

    // ---- P interlude: wave-private stripe in Pb, no barrier needed ----
    float psum[4] = {0.f, 0.f, 0.f, 0.f};
#pragma unroll
    for (int j = 0; j < 8; j++)
#pragma unroll
      for (int r = 0; r < 4; r++) {
        float e = __expf(S[j][r] * scl);
        psum[r] += e;
        Pw[(q * 4 + r) * 136 + j * 16 + lr] = f2b(e);
      }
#pragma unroll
    for (int r = 0; r < 4; r++) {
#pragma unroll
      for (int o = 1; o < 16; o <<= 1) psum[r] += __shfl_xor(psum[r], o);
      lsum[r] += psum[r];
    }
    bf16x8 Pf[4];  // A-frag: row=lr, k=t4*32+q*8 (same-wave write->read, lgkm-ordered)
#pragma unroll
    for (int t4 = 0; t4 < 4; t4++)
      Pf[t4] = *(const bf16x8*)&Pw[lr * 136 + t4 * 32 + q * 8];

    // ---- PV: 4 chunks [128 d x 128 kv]; true DMA/compute overlap here ----
#pragma unroll
    for (int dc = 0; dc < 4; dc++) {
      if (dc < 3) {
        STAGE_V(kv, dc + 1, par ^ 1);
        VMW4();
      } else if (kv < 15) {
        STAGE_K(kv + 1, 0, par ^ 1);
        VMW4();
      } else {
        VMW0();                        // final phase: nothing new in flight
      }
      __builtin_amdgcn_s_barrier();
      CFENCE();
      __builtin_amdgcn_s_setprio(1);
#pragma unroll
      for (int t4 = 0; t4 < 4; t4++)
#pragma unroll
        for (int j = 0; j < 8; j++) {
          int row = j * 16 + lr;
          bf16x8 Vf = *(const bf16x8*)&B2[par][row * 128 + (((t4 * 4 + q) ^ lr) * 8)];
          O[dc * 8 + j] = __builtin_amdgcn_mfma_f32_16x16x32_bf16(Pf[t4], Vf, O[dc * 8 + j], 0, 0, 0);
        }
      __builtin_amdgcn_s_setprio(0);
      CFENCE();
      __builtin_amdgcn_s_barrier();
      par ^= 1;
    }
  }

  // ---- epilogue: bf16 partial-O stores (no atomics) ----
  u16* op = attp + (long)half * 16384 * 512;
#pragma unroll
  for (int i = 0; i < 32; i++) {
    int col = (i >> 3) * 128 + (i & 7) * 16 + lr;
#pragma unroll
    for (int r = 0; r < 4; r++)
      op[(rowbase + w * 16 + q * 4 + r) * 512 + col] = f2b(O[i][r]);
  }
  if (lr == 0)
#pragma unroll
    for (int r = 0; r < 4; r++)
      lbp[(long)half * 16384 + rowbase + w * 16 + q * 4 + r] = lsum[r];
}

// ---------------- support kernels ----------------
// transpose for Vt (u16, post-QKV)
template <typename TS>
__global__ __launch_bounds__(1024)
void transpose_b(const TS* __restrict__ src, u16* __restrict__ dst,
                 int R, int Cc, int src_ld, long sbs, long dbs) {
  __shared__ u16 tile[32][33];
  int r = blockIdx.y * 32 + threadIdx.y;
  int c = blockIdx.x * 32 + threadIdx.x;
  tile[threadIdx.y][threadIdx.x] = to_b(src[(long)blockIdx.z * sbs + (long)r * src_ld + c]);
  __syncthreads();
  int rr = blockIdx.x * 32 + threadIdx.y;
  int cc = blockIdx.y * 32 + threadIdx.x;
  dst[(long)blockIdx.z * dbs + (long)rr * R + cc] = tile[threadIdx.x][threadIdx.y];
}

// fused prep: all weight transposes + bias concat + x->bf16 in ONE launch.
// Replaces 7 serialized small kernels (~25-30us of launch+underutilized grids)
// with one 3842-block kernel. Branches are block-uniform; bodies are the
// verified transpose_b / f32_to_bf16 / concat3 code with indices decoded from
// a flat block id.
__global__ __launch_bounds__(1024)
void prep(const float* __restrict__ Wq, const float* __restrict__ Wk,
          const float* __restrict__ Wv, const float* __restrict__ W1,
          const float* __restrict__ W2, const float* __restrict__ bq,
          const float* __restrict__ bk, const float* __restrict__ bv,
          const float* __restrict__ x, u16* __restrict__ wqkvt,
          u16* __restrict__ w1t, u16* __restrict__ w2t,
          float* __restrict__ bqkv, u16* __restrict__ xb) {
  __shared__ u16 tile[32][33];
  const int b = blockIdx.x;
  const int t = threadIdx.x;
  const int tx = t & 31, ty = t >> 5;
  if (b < 768) {
    // Wq/Wk/Wv^T: 512x512 each, 16x16 tiles of 32
    const int wsel = b >> 8, idx = b & 255;
    const int bx = idx & 15, by = idx >> 4;
    const float* src = wsel == 0 ? Wq : (wsel == 1 ? Wk : Wv);
    u16* dst = wqkvt + wsel * 512 * 512;
    tile[ty][tx] = f2b(src[(by * 32 + ty) * 512 + bx * 32 + tx]);
    __syncthreads();
    dst[(bx * 32 + ty) * 512 + by * 32 + tx] = tile[tx][ty];
  } else if (b < 1792) {
    // W1^T: src 512x2048 (ld 2048) -> w1t 2048x512; tiles x=64,y=16
    const int idx = b - 768;
    const int bx = idx & 63, by = idx >> 6;
    tile[ty][tx] = f2b(W1[(by * 32 + ty) * 2048 + bx * 32 + tx]);
    __syncthreads();
    w1t[(bx * 32 + ty) * 512 + by * 32 + tx] = tile[tx][ty];
  } else if (b < 2816) {
    // W2^T: src 2048x512 (ld 512) -> w2t 512x2048; tiles x=16,y=64
    const int idx = b - 1792;
    const int bx = idx & 15, by = idx >> 4;
    tile[ty][tx] = f2b(W2[(by * 32 + ty) * 512 + bx * 32 + tx]);
    __syncthreads();
    w2t[(bx * 32 + ty) * 2048 + by * 32 + tx] = tile[tx][ty];
  } else if (b < 3840) {
    // xb = bf16(x): 8M floats, 8192/block
    const long i = ((long)(b - 2816) * 1024 + t) * 8;
    float4 a0 = *(const float4*)(x + i);
    float4 a1 = *(const float4*)(x + i + 4);
    u16 tmp[8] = {f2b(a0.x), f2b(a0.y), f2b(a0.z), f2b(a0.w),
                  f2b(a1.x), f2b(a1.y), f2b(a1.z), f2b(a1.w)};
    *(uint4*)(xb + i) = *(uint4*)tmp;
  } else {
    // bias concat: 1536 elems
    const int i = (b - 3840) * 1024 + t;
    if (i < 512) bqkv[i] = bq[i];
    else if (i < 1024) bqkv[i] = bk[i - 512];
    else if (i < 1536) bqkv[i] = bv[i - 1024];
  }
}

// x1 = LN(x + (p0+p1)/l; g,b) -> bf16. Row 512, 1 row/wave.
__global__ __launch_bounds__(256)
void add_ln_att(const float* __restrict__ X, const u16* __restrict__ attp,
                const float* __restrict__ lbp,
                const float* __restrict__ g, const float* __restrict__ b,
                u16* __restrict__ O) {
  const int row = blockIdx.x * 4 + (threadIdx.x >> 6);
  const int lane = threadIdx.x & 63;
  const size_t base = (size_t)row * 512 + lane * 8;
  const float inv = 1.0f / (lbp[row] + lbp[16384 + row]);
  uint4 p0 = *(const uint4*)(attp + base);
  uint4 p1 = *(const uint4*)(attp + 16384L * 512 + base);
  const u16* s0 = (const u16*)&p0;
  const u16* s1 = (const u16*)&p1;
  float z[8];
  float s1a = 0.f, s2a = 0.f;
#pragma unroll
  for (int i = 0; i < 8; i++) {
    z[i] = X[base + i] + (b2f(s0[i]) + b2f(s1[i])) * inv;
    s1a += z[i]; s2a += z[i] * z[i];
  }
#pragma unroll
  for (int o = 32; o > 0; o >>= 1) { s1a += __shfl_xor(s1a, o); s2a += __shfl_xor(s2a, o); }
  const float mu = s1a * (1.0f / 512.0f);
  const float var = s2a * (1.0f / 512.0f) - mu * mu;
  const float rstd = rsqrtf(var + 1e-5f);
#pragma unroll
  for (int i = 0; i < 8; i++) {
    int c = lane * 8 + i;
    O[base + i] = f2b((z[i] - mu) * rstd * g[c] + b[c]);
  }
}

// out = LN(x1 + p0 + p1 + eb; g,b) -> fp32. Row 512, 1 row/wave.
__global__ __launch_bounds__(256)
void add_ln_ffn(const u16* __restrict__ X, const u16* __restrict__ P0,
                const u16* __restrict__ P1, const float* __restrict__ eb,
                const float* __restrict__ g, const float* __restrict__ b,
                float* __restrict__ O) {
  const int row = blockIdx.x * 4 + (threadIdx.x >> 6);
  const int lane = threadIdx.x & 63;
  const size_t base = (size_t)row * 512 + lane * 8;
  uint4 xv = *(const uint4*)(X + base);
  uint4 a0 = *(const uint4*)(P0 + base);
  uint4 a1 = *(const uint4*)(P1 + base);
  const u16* xs = (const u16*)&xv;
  const u16* s0 = (const u16*)&a0;
  const u16* s1 = (const u16*)&a1;
  float z[8];
  float s1a = 0.f, s2a = 0.f;
#pragma unroll
  for (int i = 0; i < 8; i++) {
    int c = lane * 8 + i;
    z[i] = b2f(xs[i]) + b2f(s0[i]) + b2f(s1[i]) + eb[c];
    s1a += z[i]; s2a += z[i] * z[i];
  }
#pragma unroll
  for (int o = 32; o > 0; o >>= 1) { s1a += __shfl_xor(s1a, o); s2a += __shfl_xor(s2a, o); }
  const float mu = s1a * (1.0f / 512.0f);
  const float var = s2a * (1.0f / 512.0f) - mu * mu;
  const float rstd = rsqrtf(var + 1e-5f);
#pragma unroll
  for (int i = 0; i < 8; i++) {
    int c = lane * 8 + i;
    O[base + i] = (z[i] - mu) * rstd * g[c] + b[c];
  }
}

extern "C" void kernel_launch(void* const* d_in, const int* in_sizes, int n_in,
                              void* d_out, int out_size, void* d_ws, size_t ws_size,
                              hipStream_t stream) {
  const float* x   = (const float*)d_in[0];
  const float* Wq  = (const float*)d_in[1];
  const float* bq  = (const float*)d_in[2];
  const float* Wk  = (const float*)d_in[3];
  const float* bk  = (const float*)d_in[4];
  const float* Wv  = (const float*)d_in[5];
  const float* bv  = (const float*)d_in[6];
  const float* g1  = (const float*)d_in[7];
  const float* b1  = (const float*)d_in[8];
  const float* g2  = (const float*)d_in[9];
  const float* b2  = (const float*)d_in[10];
  const float* W1  = (const float*)d_in[11];
  const float* bf1 = (const float*)d_in[12];
  const float* W2  = (const float*)d_in[13];
  const float* bf2 = (const float*)d_in[14];
  float* out = (float*)d_out;

  char* ws = (char*)d_ws;
  const size_t MB = 1048576;
  u16*   QKV   = (u16*)(ws + 0);          // [16384,1536] bf16, 48 MB
  u16*   Vt    = (u16*)(ws + 48 * MB);    // [4,512,4096] bf16, 16 MB
  u16*   attp  = (u16*)(ws + 64 * MB);    // [2][16384,512] bf16 partials, 32 MB
  u16*   h     = (u16*)(ws + 64 * MB);    // [16384,2048] bf16 (after attp dead)
  float* lbp   = (float*)(ws + 128 * MB); // [2][16384] fp32 partial row sums
  u16*   x1    = (u16*)(ws + 129 * MB);   // [16384,512] bf16, 16 MB
  u16*   ffnp  = (u16*)(ws + 145 * MB);   // [2][16384,512] bf16 partials, 32 MB
  u16*   xb    = (u16*)(ws + 145 * MB);   // bf16(x), 16 MB — dead before ffnp written
  u16*   wqkvt = (u16*)(ws + 177 * MB);   // [1536,512] bf16
  u16*   w1t   = wqkvt + 1536 * 512;      // [2048,512] bf16
  u16*   w2t   = w1t + 2048 * 512;        // [512,2048] bf16
  float* bqkv  = (float*)(w2t + 512 * 2048); // [1536] fp32

  // One fused prep launch: weight transposes + bias concat + x->bf16
  prep<<<3841, 1024, 0, stream>>>(Wq, Wk, Wv, W1, W2, bq, bk, bv, x,
                                  wqkvt, w1t, w2t, bqkv, xb);

  // Fused QKV projection
  gemm_nt<false, false><<<dim3(12, 128, 1), 256, 0, stream>>>(
      xb, wqkvt, bqkv, QKV, 1536, 512, 1, 512, 512, 1536, 0, 0, 0, 1.0f);

  // V^T per batch
  transpose_b<u16><<<dim3(16, 128, 4), dim3(32, 32), 0, stream>>>(
      QKV + 1024, Vt, 4096, 512, 1536, 4096L * 1536, 512L * 4096);

  const float scl = 0.044194173824159216f;  // 1/sqrt(512)
  // Fused attention: QBLK=128, v11 structure (verified 231us)
  flash_attn<<<dim3(256, 1, 1), 512, 0, stream>>>(QKV, Vt, attp, lbp, scl);

  // x1 = LN(x + (p0+p1)/l)
  add_ln_att<<<4096, 256, 0, stream>>>(x, attp, lbp, g1, b1, x1);
  // h = relu(x1 W1 + bf1)   (h overwrites dead attp region)
  gemm_nt<true, false><<<dim3(16, 128, 1), 256, 0, stream>>>(
      x1, w1t, bf1, h, 2048, 512, 1, 512, 512, 2048, 0, 0, 0, 1.0f);
  // ffnp[z] = h[:, z*1024:(z+1)*1024] W2[z*1024:(z+1)*1024, :] (bf16 partials)
  gemm_nt<false, false><<<dim3(4, 128, 2), 256, 0, stream>>>(
      h, w2t, nullptr, ffnp, 512, 1024, 1, 2048, 2048, 512,
      1024, 1024, 16384L * 512, 1.0f);
  // out = LN(x1 + p0 + p1 + bf2) -> fp32
  add_ln_ffn<<<4096, 256, 0, stream>>>(
      x1, ffnp, ffnp + 16384L * 512, bf2, g2, b2, out);
}

// Round 12
// 484.203 us; speedup vs baseline: 1.4693x; 1.0379x over previous
//
#include <hip/hip_runtime.h>
#include <hip/hip_bf16.h>

typedef unsigned short u16;
typedef short bf16x8 __attribute__((ext_vector_type(8)));
typedef float f32x4 __attribute__((ext_vector_type(4)));

__device__ __forceinline__ float b2f(u16 u) {
  union { float f; unsigned int i; } v; v.i = ((unsigned int)u) << 16; return v.f;
}
__device__ __forceinline__ u16 f2b(float f) {
  union { float f; unsigned int i; } v; v.f = f;
  unsigned int r = v.i + 0x7fffu + ((v.i >> 16) & 1u);
  return (u16)(r >> 16);
}
__device__ __forceinline__ u16 to_b(float v) { return f2b(v); }
__device__ __forceinline__ u16 to_b(u16 v) { return v; }

// async 16B global -> LDS (dest = uniform lds base + lane*16)
__device__ __forceinline__ void gl_lds16(const u16* g, u16* l) {
  __builtin_amdgcn_global_load_lds(
      (const __attribute__((address_space(1))) unsigned int*)g,
      (__attribute__((address_space(3))) unsigned int*)l, 16, 0, 0);
}

#define VMW4()  asm volatile("s_waitcnt vmcnt(4)" ::: "memory")
#define VMW0()  asm volatile("s_waitcnt vmcnt(0)" ::: "memory")
#define CFENCE() asm volatile("" ::: "memory")

// ---------------- generic NT GEMM (single-buffer, verified) + XCD swizzle ----------------
template <bool RELU, bool ATOMIC>
__global__ __launch_bounds__(256)
void gemm_nt(const u16* __restrict__ A, const u16* __restrict__ Bt,
             const float* __restrict__ bias, void* __restrict__ Cv,
             int N, int K, int nsplit, int lda, int ldb, int ldc,
             long sA, long sB, long sC, float scale) {
  __shared__ __align__(16) u16 As[128 * 64];
  __shared__ __align__(16) u16 Bs[128 * 64];
  const int z = blockIdx.z;
  const int batch = z / nsplit, split = z - batch * nsplit;
  const int Ks = K / nsplit;
  const u16* Ab = A + (long)batch * sA + (long)split * Ks;
  const u16* Bb = Bt + (long)batch * sB + (long)split * Ks;
  // XCD swizzle: xcd = flat%8 gets contiguous M-panel chunk (bijective: gridDim.y%8==0)
  const int f = blockIdx.x + gridDim.x * blockIdx.y;
  const int xcd = f & 7, idx = f >> 3;
  const int bx = idx % gridDim.x;
  const int by = xcd * (gridDim.y >> 3) + idx / gridDim.x;
  const int m0 = by * 128, n0 = bx * 128;
  const int t = threadIdx.x, w = t >> 6, lane = t & 63;
  const int wm = (w >> 1) * 64, wn = (w & 1) * 64;
  const int lr = lane & 15, q = lane >> 4;

  int srow[4], scol[4];
#pragma unroll
  for (int i = 0; i < 4; i++) {
    int n = w * 256 + i * 64 + lane;
    srow[i] = n >> 3;
    scol[i] = (((n & 7) ^ ((n >> 3) & 7)) * 8);
  }

  f32x4 acc[4][4];
#pragma unroll
  for (int i = 0; i < 4; i++)
#pragma unroll
    for (int j = 0; j < 4; j++) acc[i][j] = (f32x4){0.f, 0.f, 0.f, 0.f};

  for (int k0 = 0; k0 < Ks; k0 += 64) {
#pragma unroll
    for (int i = 0; i < 4; i++)
      gl_lds16(Ab + (long)(m0 + srow[i]) * lda + k0 + scol[i], &As[(w * 256 + i * 64) * 8]);
#pragma unroll
    for (int i = 0; i < 4; i++)
      gl_lds16(Bb + (long)(n0 + srow[i]) * ldb + k0 + scol[i], &Bs[(w * 256 + i * 64) * 8]);
    __syncthreads();
#pragma unroll
    for (int kk = 0; kk < 2; kk++) {
      bf16x8 af[4], bfr[4];
#pragma unroll
      for (int i = 0; i < 4; i++) {
        int row = wm + i * 16 + lr;
        af[i] = *(const bf16x8*)&As[row * 64 + (((kk * 4 + q) ^ (row & 7)) * 8)];
      }
#pragma unroll
      for (int j = 0; j < 4; j++) {
        int row = wn + j * 16 + lr;
        bfr[j] = *(const bf16x8*)&Bs[row * 64 + (((kk * 4 + q) ^ (row & 7)) * 8)];
      }
#pragma unroll
      for (int i = 0; i < 4; i++)
#pragma unroll
        for (int j = 0; j < 4; j++)
          acc[i][j] = __builtin_amdgcn_mfma_f32_16x16x32_bf16(af[i], bfr[j], acc[i][j], 0, 0, 0);
    }
    __syncthreads();
  }

#pragma unroll
  for (int j = 0; j < 4; j++) {
    int cg = n0 + wn + j * 16 + lr;
    float bb = (!ATOMIC && bias) ? bias[cg] : 0.0f;
#pragma unroll
    for (int i = 0; i < 4; i++) {
      int rbase = m0 + wm + i * 16 + q * 4;
#pragma unroll
      for (int r = 0; r < 4; r++) {
        float vv = acc[i][j][r] * scale;
        if (ATOMIC) {
          atomicAdd((float*)Cv + (long)batch * sC + (long)(rbase + r) * ldc + cg, vv);
        } else {
          vv += bb;
          if (RELU) vv = fmaxf(vv, 0.0f);
          ((u16*)Cv)[(long)batch * sC + (long)(rbase + r) * ldc + cg] = f2b(vv);
        }
      }
    }
  }
}

// ---------------- fused flash attention v11 (verified 231us, local optimum) ----------------
#define STAGE_K(kvv, kcc, sel)                                               \
  {                                                                          \
    _Pragma("unroll") for (int rr = 0; rr < 4; rr++)                         \
        gl_lds16(Kbase + (long)((kvv) * 128 + srow[rr]) * 1536 +             \
                     (kcc) * 128 + scol8[rr],                                \
                 &B2[(sel)][ldsd[rr]]);                                      \
  }
#define STAGE_V(kvv, dcc, sel)                                               \
  {                                                                          \
    _Pragma("unroll") for (int rr = 0; rr < 4; rr++)                         \
        gl_lds16(Vtb + (long)((dcc) * 128 + srow[rr]) * 4096 +               \
                     (kvv) * 128 + scol8[rr],                                \
                 &B2[(sel)][ldsd[rr]]);                                      \
  }

__global__ __launch_bounds__(512, 2)
void flash_attn(const u16* __restrict__ QKV, const u16* __restrict__ Vt,
                u16* __restrict__ attp, float* __restrict__ lbp, float scl) {
  __shared__ __align__(16) u16 B2[2][128 * 128];  // 2 x 32 KB ping-pong (K/V chunks)
  __shared__ __align__(16) u16 Pb[128 * 136];     // 34 KB P stripes, wave-private
  const int flat = blockIdx.x;
  const int batch = (flat & 7) >> 1, half = flat & 1, qt = flat >> 3;
  const int t = threadIdx.x, w = t >> 6, lane = t & 63;
  const int lr = lane & 15, q = lane >> 4;
  const long rowbase = (long)batch * 4096 + qt * 128;
  const u16* Qrow  = QKV + (rowbase + w * 16 + lr) * 1536;                  // Q cols [0,512)
  const u16* Kbase = QKV + ((long)batch * 4096 + half * 2048) * 1536 + 512; // K cols [512,1024)
  const u16* Vtb   = Vt + (long)batch * 512 * 4096 + half * 2048;           // [512,4096] ld 4096
  u16* Pw = &Pb[w * (16 * 136)];

  int srow[4], scol8[4], ldsd[4];
#pragma unroll
  for (int rr = 0; rr < 4; rr++) {
    int n = rr * 512 + t;
    srow[rr] = n >> 4;
    scol8[rr] = ((n & 15) ^ ((n >> 4) & 15)) * 8;
    ldsd[rr] = (rr * 512 + w * 64) * 8;  // wave-uniform base; DMA adds lane*16B
  }

  f32x4 O[32];  // O[dc*8+j]: row=q*4+r, col=dc*128 + j*16 + lr
#pragma unroll
  for (int i = 0; i < 32; i++) O[i] = (f32x4){0.f, 0.f, 0.f, 0.f};
  float lsum[4] = {0.f, 0.f, 0.f, 0.f};

  STAGE_K(0, 0, 0);  // prologue: first chunk in flight; drained by kc=0's wait
  int par = 0;

  for (int kv = 0; kv < 16; kv++) {
    f32x4 S[8];
#pragma unroll
    for (int j = 0; j < 8; j++) S[j] = (f32x4){0.f, 0.f, 0.f, 0.f};

    // ---- QK^T: 4 chunks [128 kv x 128 k]; Qf issued BEFORE next stage ----
#pragma unroll
    for (int kc = 0; kc < 4; kc++) {
      bf16x8 Qf[4];  // older than stage(next) -> VMW4 completes them, no drain
#pragma unroll
      for (int ss = 0; ss < 4; ss++)
        Qf[ss] = *(const bf16x8*)(Qrow + kc * 128 + ss * 32 + q * 8);
      __builtin_amdgcn_sched_barrier(0);
      if (kc < 3) { STAGE_K(kv, kc + 1, par ^ 1); }
      else        { STAGE_V(kv, 0, par ^ 1); }
      VMW4();                          // stage(cur)+Qf done; stage(next) in flight
      __builtin_amdgcn_s_barrier();    // ... block-globally
      CFENCE();
      __builtin_amdgcn_s_setprio(1);
#pragma unroll
      for (int ss = 0; ss < 4; ss++)
#pragma unroll
        for (int j = 0; j < 8; j++) {
          int row = j * 16 + lr;
          bf16x8 Kf = *(const bf16x8*)&B2[par][row * 128 + (((ss * 4 + q) ^ lr) * 8)];
          S[j] = __builtin_amdgcn_mfma_f32_16x16x32_bf16(Qf[ss], Kf, S[j], 0, 0, 0);
        }
      __builtin_amdgcn_s_setprio(0);
      CFENCE();
      __builtin_amdgcn_s_barrier();    // reads done before next DMA overwrites
      par ^= 1;
    }

    // ---- P interlude: wave-private stripe in Pb, no barrier needed ----
    float psum[4] = {0.f, 0.f, 0.f, 0.f};
#pragma unroll
    for (int j = 0; j < 8; j++)
#pragma unroll
      for (int r = 0; r < 4; r++) {
        float e = __expf(S[j][r] * scl);
        psum[r] += e;
        Pw[(q * 4 + r) * 136 + j * 16 + lr] = f2b(e);
      }
#pragma unroll
    for (int r = 0; r < 4; r++) {
#pragma unroll
      for (int o = 1; o < 16; o <<= 1) psum[r] += __shfl_xor(psum[r], o);
      lsum[r] += psum[r];
    }
    bf16x8 Pf[4];  // A-frag: row=lr, k=t4*32+q*8 (same-wave write->read, lgkm-ordered)
#pragma unroll
    for (int t4 = 0; t4 < 4; t4++)
      Pf[t4] = *(const bf16x8*)&Pw[lr * 136 + t4 * 32 + q * 8];

    // ---- PV: 4 chunks [128 d x 128 kv]; true DMA/compute overlap here ----
#pragma unroll
    for (int dc = 0; dc < 4; dc++) {
      if (dc < 3) {
        STAGE_V(kv, dc + 1, par ^ 1);
        VMW4();
      } else if (kv < 15) {
        STAGE_K(kv + 1, 0, par ^ 1);
        VMW4();
      } else {
        VMW0();                        // final phase: nothing new in flight
      }
      __builtin_amdgcn_s_barrier();
      CFENCE();
      __builtin_amdgcn_s_setprio(1);
#pragma unroll
      for (int t4 = 0; t4 < 4; t4++)
#pragma unroll
        for (int j = 0; j < 8; j++) {
          int row = j * 16 + lr;
          bf16x8 Vf = *(const bf16x8*)&B2[par][row * 128 + (((t4 * 4 + q) ^ lr) * 8)];
          O[dc * 8 + j] = __builtin_amdgcn_mfma_f32_16x16x32_bf16(Pf[t4], Vf, O[dc * 8 + j], 0, 0, 0);
        }
      __builtin_amdgcn_s_setprio(0);
      CFENCE();
      __builtin_amdgcn_s_barrier();
      par ^= 1;
    }
  }

  // ---- epilogue: bf16 partial-O stores (no atomics) ----
  u16* op = attp + (long)half * 16384 * 512;
#pragma unroll
  for (int i = 0; i < 32; i++) {
    int col = (i >> 3) * 128 + (i & 7) * 16 + lr;
#pragma unroll
    for (int r = 0; r < 4; r++)
      op[(rowbase + w * 16 + q * 4 + r) * 512 + col] = f2b(O[i][r]);
  }
  if (lr == 0)
#pragma unroll
    for (int r = 0; r < 4; r++)
      lbp[(long)half * 16384 + rowbase + w * 16 + q * 4 + r] = lsum[r];
}

// ---------------- support kernels ----------------
// transpose for Vt (u16, post-QKV)
template <typename TS>
__global__ __launch_bounds__(1024)
void transpose_b(const TS* __restrict__ src, u16* __restrict__ dst,
                 int R, int Cc, int src_ld, long sbs, long dbs) {
  __shared__ u16 tile[32][33];
  int r = blockIdx.y * 32 + threadIdx.y;
  int c = blockIdx.x * 32 + threadIdx.x;
  tile[threadIdx.y][threadIdx.x] = to_b(src[(long)blockIdx.z * sbs + (long)r * src_ld + c]);
  __syncthreads();
  int rr = blockIdx.x * 32 + threadIdx.y;
  int cc = blockIdx.y * 32 + threadIdx.x;
  dst[(long)blockIdx.z * dbs + (long)rr * R + cc] = tile[threadIdx.x][threadIdx.y];
}

// fused prep: all weight transposes + bias concat + x->bf16 in ONE launch.
// FIX (r11 post-mortem): bias concat needs 1536 elems = 2 blocks of 1024;
// r11 launched 3841 blocks so bqkv[1024:1536] (V bias) was never written
// (absmax 0.03125 -> 0.078125). Grid is now 3842 with an i<1536 guard.
__global__ __launch_bounds__(1024)
void prep(const float* __restrict__ Wq, const float* __restrict__ Wk,
          const float* __restrict__ Wv, const float* __restrict__ W1,
          const float* __restrict__ W2, const float* __restrict__ bq,
          const float* __restrict__ bk, const float* __restrict__ bv,
          const float* __restrict__ x, u16* __restrict__ wqkvt,
          u16* __restrict__ w1t, u16* __restrict__ w2t,
          float* __restrict__ bqkv, u16* __restrict__ xb) {
  __shared__ u16 tile[32][33];
  const int b = blockIdx.x;
  const int t = threadIdx.x;
  const int tx = t & 31, ty = t >> 5;
  if (b < 768) {
    // Wq/Wk/Wv^T: 512x512 each, 16x16 tiles of 32
    const int wsel = b >> 8, idx = b & 255;
    const int bx = idx & 15, by = idx >> 4;
    const float* src = wsel == 0 ? Wq : (wsel == 1 ? Wk : Wv);
    u16* dst = wqkvt + wsel * 512 * 512;
    tile[ty][tx] = f2b(src[(by * 32 + ty) * 512 + bx * 32 + tx]);
    __syncthreads();
    dst[(bx * 32 + ty) * 512 + by * 32 + tx] = tile[tx][ty];
  } else if (b < 1792) {
    // W1^T: src 512x2048 (ld 2048) -> w1t 2048x512; tiles x=64,y=16
    const int idx = b - 768;
    const int bx = idx & 63, by = idx >> 6;
    tile[ty][tx] = f2b(W1[(by * 32 + ty) * 2048 + bx * 32 + tx]);
    __syncthreads();
    w1t[(bx * 32 + ty) * 512 + by * 32 + tx] = tile[tx][ty];
  } else if (b < 2816) {
    // W2^T: src 2048x512 (ld 512) -> w2t 512x2048; tiles x=16,y=64
    const int idx = b - 1792;
    const int bx = idx & 15, by = idx >> 4;
    tile[ty][tx] = f2b(W2[(by * 32 + ty) * 512 + bx * 32 + tx]);
    __syncthreads();
    w2t[(bx * 32 + ty) * 2048 + by * 32 + tx] = tile[tx][ty];
  } else if (b < 3840) {
    // xb = bf16(x): 8M floats, 8192/block
    const long i = ((long)(b - 2816) * 1024 + t) * 8;
    float4 a0 = *(const float4*)(x + i);
    float4 a1 = *(const float4*)(x + i + 4);
    u16 tmp[8] = {f2b(a0.x), f2b(a0.y), f2b(a0.z), f2b(a0.w),
                  f2b(a1.x), f2b(a1.y), f2b(a1.z), f2b(a1.w)};
    *(uint4*)(xb + i) = *(uint4*)tmp;
  } else {
    // bias concat: 1536 elems across 2 blocks (b = 3840, 3841)
    const int i = (b - 3840) * 1024 + t;
    if (i < 512) bqkv[i] = bq[i];
    else if (i < 1024) bqkv[i] = bk[i - 512];
    else if (i < 1536) bqkv[i] = bv[i - 1024];
  }
}

// x1 = LN(x + (p0+p1)/l; g,b) -> bf16. Row 512, 1 row/wave.
__global__ __launch_bounds__(256)
void add_ln_att(const float* __restrict__ X, const u16* __restrict__ attp,
                const float* __restrict__ lbp,
                const float* __restrict__ g, const float* __restrict__ b,
                u16* __restrict__ O) {
  const int row = blockIdx.x * 4 + (threadIdx.x >> 6);
  const int lane = threadIdx.x & 63;
  const size_t base = (size_t)row * 512 + lane * 8;
  const float inv = 1.0f / (lbp[row] + lbp[16384 + row]);
  uint4 p0 = *(const uint4*)(attp + base);
  uint4 p1 = *(const uint4*)(attp + 16384L * 512 + base);
  const u16* s0 = (const u16*)&p0;
  const u16* s1 = (const u16*)&p1;
  float z[8];
  float s1a = 0.f, s2a = 0.f;
#pragma unroll
  for (int i = 0; i < 8; i++) {
    z[i] = X[base + i] + (b2f(s0[i]) + b2f(s1[i])) * inv;
    s1a += z[i]; s2a += z[i] * z[i];
  }
#pragma unroll
  for (int o = 32; o > 0; o >>= 1) { s1a += __shfl_xor(s1a, o); s2a += __shfl_xor(s2a, o); }
  const float mu = s1a * (1.0f / 512.0f);
  const float var = s2a * (1.0f / 512.0f) - mu * mu;
  const float rstd = rsqrtf(var + 1e-5f);
#pragma unroll
  for (int i = 0; i < 8; i++) {
    int c = lane * 8 + i;
    O[base + i] = f2b((z[i] - mu) * rstd * g[c] + b[c]);
  }
}

// out = LN(x1 + p0 + p1 + eb; g,b) -> fp32. Row 512, 1 row/wave.
__global__ __launch_bounds__(256)
void add_ln_ffn(const u16* __restrict__ X, const u16* __restrict__ P0,
                const u16* __restrict__ P1, const float* __restrict__ eb,
                const float* __restrict__ g, const float* __restrict__ b,
                float* __restrict__ O) {
  const int row = blockIdx.x * 4 + (threadIdx.x >> 6);
  const int lane = threadIdx.x & 63;
  const size_t base = (size_t)row * 512 + lane * 8;
  uint4 xv = *(const uint4*)(X + base);
  uint4 a0 = *(const uint4*)(P0 + base);
  uint4 a1 = *(const uint4*)(P1 + base);
  const u16* xs = (const u16*)&xv;
  const u16* s0 = (const u16*)&a0;
  const u16* s1 = (const u16*)&a1;
  float z[8];
  float s1a = 0.f, s2a = 0.f;
#pragma unroll
  for (int i = 0; i < 8; i++) {
    int c = lane * 8 + i;
    z[i] = b2f(xs[i]) + b2f(s0[i]) + b2f(s1[i]) + eb[c];
    s1a += z[i]; s2a += z[i] * z[i];
  }
#pragma unroll
  for (int o = 32; o > 0; o >>= 1) { s1a += __shfl_xor(s1a, o); s2a += __shfl_xor(s2a, o); }
  const float mu = s1a * (1.0f / 512.0f);
  const float var = s2a * (1.0f / 512.0f) - mu * mu;
  const float rstd = rsqrtf(var + 1e-5f);
#pragma unroll
  for (int i = 0; i < 8; i++) {
    int c = lane * 8 + i;
    O[base + i] = (z[i] - mu) * rstd * g[c] + b[c];
  }
}

extern "C" void kernel_launch(void* const* d_in, const int* in_sizes, int n_in,
                              void* d_out, int out_size, void* d_ws, size_t ws_size,
                              hipStream_t stream) {
  const float* x   = (const float*)d_in[0];
  const float* Wq  = (const float*)d_in[1];
  const float* bq  = (const float*)d_in[2];
  const float* Wk  = (const float*)d_in[3];
  const float* bk  = (const float*)d_in[4];
  const float* Wv  = (const float*)d_in[5];
  const float* bv  = (const float*)d_in[6];
  const float* g1  = (const float*)d_in[7];
  const float* b1  = (const float*)d_in[8];
  const float* g2  = (const float*)d_in[9];
  const float* b2  = (const float*)d_in[10];
  const float* W1  = (const float*)d_in[11];
  const float* bf1 = (const float*)d_in[12];
  const float* W2  = (const float*)d_in[13];
  const float* bf2 = (const float*)d_in[14];
  float* out = (float*)d_out;

  char* ws = (char*)d_ws;
  const size_t MB = 1048576;
  u16*   QKV   = (u16*)(ws + 0);          // [16384,1536] bf16, 48 MB
  u16*   Vt    = (u16*)(ws + 48 * MB);    // [4,512,4096] bf16, 16 MB
  u16*   attp  = (u16*)(ws + 64 * MB);    // [2][16384,512] bf16 partials, 32 MB
  u16*   h     = (u16*)(ws + 64 * MB);    // [16384,2048] bf16 (after attp dead)
  float* lbp   = (float*)(ws + 128 * MB); // [2][16384] fp32 partial row sums
  u16*   x1    = (u16*)(ws + 129 * MB);   // [16384,512] bf16, 16 MB
  u16*   ffnp  = (u16*)(ws + 145 * MB);   // [2][16384,512] bf16 partials, 32 MB
  u16*   xb    = (u16*)(ws + 145 * MB);   // bf16(x), 16 MB — dead before ffnp written
  u16*   wqkvt = (u16*)(ws + 177 * MB);   // [1536,512] bf16
  u16*   w1t   = wqkvt + 1536 * 512;      // [2048,512] bf16
  u16*   w2t   = w1t + 2048 * 512;        // [512,2048] bf16
  float* bqkv  = (float*)(w2t + 512 * 2048); // [1536] fp32

  // One fused prep launch: weight transposes + bias concat + x->bf16
  // (3842 blocks: concat needs blocks 3840 AND 3841 — r11 bug fixed)
  prep<<<3842, 1024, 0, stream>>>(Wq, Wk, Wv, W1, W2, bq, bk, bv, x,
                                  wqkvt, w1t, w2t, bqkv, xb);

  // Fused QKV projection
  gemm_nt<false, false><<<dim3(12, 128, 1), 256, 0, stream>>>(
      xb, wqkvt, bqkv, QKV, 1536, 512, 1, 512, 512, 1536, 0, 0, 0, 1.0f);

  // V^T per batch
  transpose_b<u16><<<dim3(16, 128, 4), dim3(32, 32), 0, stream>>>(
      QKV + 1024, Vt, 4096, 512, 1536, 4096L * 1536, 512L * 4096);

  const float scl = 0.044194173824159216f;  // 1/sqrt(512)
  // Fused attention: QBLK=128, v11 structure (verified 231us)
  flash_attn<<<dim3(256, 1, 1), 512, 0, stream>>>(QKV, Vt, attp, lbp, scl);

  // x1 = LN(x + (p0+p1)/l)
  add_ln_att<<<4096, 256, 0, stream>>>(x, attp, lbp, g1, b1, x1);
  // h = relu(x1 W1 + bf1)   (h overwrites dead attp region)
  gemm_nt<true, false><<<dim3(16, 128, 1), 256, 0, stream>>>(
      x1, w1t, bf1, h, 2048, 512, 1, 512, 512, 2048, 0, 0, 0, 1.0f);
  // ffnp[z] = h[:, z*1024:(z+1)*1024] W2[z*1024:(z+1)*1024, :] (bf16 partials)
  gemm_nt<false, false><<<dim3(4, 128, 2), 256, 0, stream>>>(
      h, w2t, nullptr, ffnp, 512, 1024, 1, 2048, 2048, 512,
      1024, 1024, 16384L * 512, 1.0f);
  // out = LN(x1 + p0 + p1 + bf2) -> fp32
  add_ln_ffn<<<4096, 256, 0, stream>>>(
      x1, ffnp, ffnp + 16384L * 512, bf2, g2, b2, out);
}